// Round 5
// baseline (541.083 us; speedup 1.0000x reference)
//
#include <hip/hip_runtime.h>
#include <math.h>

#define DIMC 512
#define HW 4096
#define SCALE 0.125f
#define EPSN 1e-12f

typedef __attribute__((ext_vector_type(8))) short bf16x8;
typedef __attribute__((ext_vector_type(4))) float f32x4;

__device__ __forceinline__ unsigned short f2bf(float f) {
    union { float f; unsigned int u; } v; v.f = f;
    unsigned int u = v.u;
    return (unsigned short)((u + 0x7fffu + ((u >> 16) & 1u)) >> 16);
}

union Pack8 { int4 v; unsigned short u[8]; };

// ---------------------------------------------------------------------------
// P1: convert Wq,Wk,Wv fp32 -> Wb bf16 [3][512][512]
// ---------------------------------------------------------------------------
__global__ __launch_bounds__(256) void convert_w(
    const float* __restrict__ Wq, const float* __restrict__ Wk,
    const float* __restrict__ Wv, unsigned short* __restrict__ Wb)
{
    int i = (blockIdx.x * 256 + threadIdx.x) * 4;
    int m = i >> 18;
    int off = i & 262143;
    const float* s = (m == 0) ? Wq : (m == 1) ? Wk : Wv;
    float4 v4 = *(const float4*)(s + off);
    ushort4 o;
    o.x = f2bf(v4.x); o.y = f2bf(v4.y); o.z = f2bf(v4.z); o.w = f2bf(v4.w);
    *(ushort4*)(Wb + i) = o;
}

// ---------------------------------------------------------------------------
// P2: transpose+convert x[b][c][n] fp32 -> xT[b][n][c] bf16
// ---------------------------------------------------------------------------
__global__ __launch_bounds__(256) void transpose_x(
    const float* __restrict__ x, unsigned short* __restrict__ xT)
{
    const int b  = blockIdx.z;
    const int c0 = blockIdx.y * 64;
    const int n0 = blockIdx.x * 64;
    __shared__ unsigned short sT[64][65];
    const int t = threadIdx.x;
    #pragma unroll
    for (int i = 0; i < 4; ++i) {
        int ch = t + i * 256;
        int r = ch >> 4, col4 = (ch & 15) * 4;
        float4 v4 = *(const float4*)(x + ((size_t)b * DIMC + c0 + r) * HW + n0 + col4);
        sT[r][col4 + 0] = f2bf(v4.x); sT[r][col4 + 1] = f2bf(v4.y);
        sT[r][col4 + 2] = f2bf(v4.z); sT[r][col4 + 3] = f2bf(v4.w);
    }
    __syncthreads();
    #pragma unroll
    for (int i = 0; i < 2; ++i) {
        int ch = t + i * 256;
        int n = ch >> 3, cc = (ch & 7) * 8;
        Pack8 pk;
        #pragma unroll
        for (int e = 0; e < 8; ++e) pk.u[e] = sT[cc + e][n];
        *(int4*)(xT + ((size_t)b * HW + n0 + n) * DIMC + c0 + cc) = pk.v;
    }
}

// ---------------------------------------------------------------------------
// K1: MFMA QKV projection, SPLIT per output (which = blockIdx.z>>3) to keep
// register pressure low (R4 post-mortem: fused 3-acc version spilled ->
// 746MB phantom HBM writes). Keeps: LDS-staged coalesced int4 epilogue,
// v stored directly transposed, fused masked-sumsq atomics.
// BM=64(j) x BN=128(n), BK=64, 4 waves (2x2), acc 2x4.
// ---------------------------------------------------------------------------
__global__ __launch_bounds__(256, 2) void qkv_mfma(
    const unsigned short* __restrict__ Wb, const unsigned short* __restrict__ xT,
    const float* __restrict__ mask,
    unsigned short* __restrict__ q, unsigned short* __restrict__ k,
    unsigned short* __restrict__ vT, float* __restrict__ sumsq)
{
    const int which = blockIdx.z >> 3;   // 0=q,1=k,2=v
    const int b     = blockIdx.z & 7;
    const int j0 = blockIdx.y * 64;
    const int n0 = blockIdx.x * 128;
    const unsigned short* A = Wb + (size_t)which * 262144;
    const unsigned short* B = xT + (size_t)b * HW * DIMC;

    // 0..8191 sA | 8192..24575 sB ; epilogue staging reuses [0..18431]
    __shared__ __align__(16) char sm[24576];

    const int t = threadIdx.x, lane = t & 63, w = t >> 6;
    const int wm = w >> 1, wn = w & 1;

    f32x4 zero = {0.f, 0.f, 0.f, 0.f};
    f32x4 acc[2][4];
    #pragma unroll
    for (int m = 0; m < 2; ++m)
        #pragma unroll
        for (int n = 0; n < 4; ++n) acc[m][n] = zero;

    int offA[2], offB[4];
    const unsigned short *gA[2], *gB[4];
    #pragma unroll
    for (int i = 0; i < 2; ++i) {
        int ch = t + i * 256, r = ch >> 3, sl = ch & 7;
        offA[i] = r * 128 + ((sl ^ (r & 7)) << 4);
        gA[i] = A + (size_t)(j0 + r) * DIMC + sl * 8;
    }
    #pragma unroll
    for (int i = 0; i < 4; ++i) {
        int ch = t + i * 256, r = ch >> 3, sl = ch & 7;
        offB[i] = r * 128 + ((sl ^ (r & 7)) << 4);
        gB[i] = B + (size_t)(n0 + r) * DIMC + sl * 8;
    }

    int4 ra[2], rb[4];
    #pragma unroll
    for (int i = 0; i < 2; ++i) ra[i] = *(const int4*)(gA[i]);
    #pragma unroll
    for (int i = 0; i < 4; ++i) rb[i] = *(const int4*)(gB[i]);

    for (int c0 = 0; c0 < DIMC; c0 += 64) {
        __syncthreads();
        #pragma unroll
        for (int i = 0; i < 2; ++i) *(int4*)(sm + offA[i]) = ra[i];
        #pragma unroll
        for (int i = 0; i < 4; ++i) *(int4*)(sm + 8192 + offB[i]) = rb[i];
        __syncthreads();
        if (c0 + 64 < DIMC) {
            #pragma unroll
            for (int i = 0; i < 2; ++i) ra[i] = *(const int4*)(gA[i] + c0 + 64);
            #pragma unroll
            for (int i = 0; i < 4; ++i) rb[i] = *(const int4*)(gB[i] + c0 + 64);
        }
        #pragma unroll
        for (int s = 0; s < 2; ++s) {
            bf16x8 af[2], bfr[4];
            #pragma unroll
            for (int m = 0; m < 2; ++m) {
                int r = wm * 32 + m * 16 + (lane & 15);
                int byte = r * 128 + s * 64 + ((lane >> 4) << 4);
                byte ^= (r & 7) << 4;
                af[m] = *(const bf16x8*)(sm + byte);
            }
            #pragma unroll
            for (int n = 0; n < 4; ++n) {
                int r = wn * 64 + n * 16 + (lane & 15);
                int byte = r * 128 + s * 64 + ((lane >> 4) << 4);
                byte ^= (r & 7) << 4;
                bfr[n] = *(const bf16x8*)(sm + 8192 + byte);
            }
            #pragma unroll
            for (int m = 0; m < 2; ++m)
                #pragma unroll
                for (int n = 0; n < 4; ++n)
                    acc[m][n] = __builtin_amdgcn_mfma_f32_16x16x32_bf16(
                        af[m], bfr[n], acc[m][n], 0, 0, 0);
        }
    }

    unsigned short* st = (unsigned short*)sm;

    if (which < 2) {
        // apply mask, fused sumsq (16-lane row reduce -> 1 atomic/row-slice)
        float mv[4];
        #pragma unroll
        for (int n = 0; n < 4; ++n)
            mv[n] = mask[(size_t)b * HW + n0 + wn * 64 + n * 16 + (lane & 15)];
        #pragma unroll
        for (int m = 0; m < 2; ++m)
            #pragma unroll
            for (int n = 0; n < 4; ++n)
                #pragma unroll
                for (int r4 = 0; r4 < 4; ++r4)
                    acc[m][n][r4] *= mv[n];
        #pragma unroll
        for (int m = 0; m < 2; ++m)
            #pragma unroll
            for (int r4 = 0; r4 < 4; ++r4) {
                float s = 0.f;
                #pragma unroll
                for (int n = 0; n < 4; ++n)
                    s = fmaf(acc[m][n][r4], acc[m][n][r4], s);
                s += __shfl_xor(s, 8, 16);
                s += __shfl_xor(s, 4, 16);
                s += __shfl_xor(s, 2, 16);
                s += __shfl_xor(s, 1, 16);
                if ((lane & 15) == 0) {
                    int j = j0 + wm * 32 + m * 16 + ((lane >> 4) << 2) + r4;
                    atomicAdd(&sumsq[which * 4096 + b * DIMC + j], s);
                }
            }

        // stage [64j][128n] @ stride 136 shorts, then coalesced int4 stores
        unsigned short* outp = which ? k : q;
        __syncthreads();
        #pragma unroll
        for (int m = 0; m < 2; ++m)
            #pragma unroll
            for (int n = 0; n < 4; ++n)
                #pragma unroll
                for (int r4 = 0; r4 < 4; ++r4) {
                    int jl = wm * 32 + m * 16 + ((lane >> 4) << 2) + r4;
                    int nl = wn * 64 + n * 16 + (lane & 15);
                    st[jl * 136 + nl] = f2bf(acc[m][n][r4]);
                }
        __syncthreads();
        #pragma unroll
        for (int it = 0; it < 4; ++it) {
            int idx = t + it * 256, jl = idx >> 4, l16 = idx & 15;
            int4 pv = *(int4*)(sm + jl * 272 + l16 * 16);
            *(int4*)(outp + ((size_t)b * DIMC + j0 + jl) * HW + n0 + l16 * 8) = pv;
        }
    } else {
        // v: stage transposed [128n][64j] @ stride 72 shorts, coalesced stores
        __syncthreads();
        #pragma unroll
        for (int m = 0; m < 2; ++m)
            #pragma unroll
            for (int n = 0; n < 4; ++n)
                #pragma unroll
                for (int r4 = 0; r4 < 4; ++r4) {
                    int jl = wm * 32 + m * 16 + ((lane >> 4) << 2) + r4;
                    int nl = wn * 64 + n * 16 + (lane & 15);
                    st[nl * 72 + jl] = f2bf(acc[m][n][r4]);
                }
        __syncthreads();
        #pragma unroll
        for (int it = 0; it < 4; ++it) {
            int idx = t + it * 256, nl = idx >> 3, c8 = idx & 7;
            int4 pv = *(int4*)(sm + nl * 144 + c8 * 16);
            *(int4*)(vT + ((size_t)b * HW + n0 + nl) * DIMC + j0 + c8 * 8) = pv;
        }
    }
}

// ---------------------------------------------------------------------------
// K3: MFMA attention logits (NT GEMM).
// Spart[bh][chunk][r][c] = sum_{n in chunk} q[r][n]*k[c][n], chunk=512 wide.
// ---------------------------------------------------------------------------
__global__ __launch_bounds__(256) void attn_mfma(
    const unsigned short* __restrict__ q, const unsigned short* __restrict__ k,
    float* __restrict__ Spart)
{
    const int bh = blockIdx.x;
    const int chunk = blockIdx.y;
    const unsigned short* Q = q + (size_t)bh * 64 * HW;
    const unsigned short* K = k + (size_t)bh * 64 * HW;

    __shared__ unsigned short sQ[64 * 64];
    __shared__ unsigned short sK[64 * 64];

    const int t = threadIdx.x, lane = t & 63, w = t >> 6;
    const int wm = w >> 1, wn = w & 1;

    f32x4 zero = {0.f, 0.f, 0.f, 0.f};
    f32x4 acc[2][2];
    #pragma unroll
    for (int m = 0; m < 2; ++m)
        #pragma unroll
        for (int n = 0; n < 2; ++n) acc[m][n] = zero;

    int offs[2];
    const unsigned short* gQ[2];
    const unsigned short* gK[2];
    const int nb = chunk * 512;
    #pragma unroll
    for (int i = 0; i < 2; ++i) {
        int ch = t + i * 256, r = ch >> 3, sl = ch & 7;
        offs[i] = r * 128 + ((sl ^ (r & 7)) << 4);
        gQ[i] = Q + (size_t)r * HW + nb + sl * 8;
        gK[i] = K + (size_t)r * HW + nb + sl * 8;
    }

    int4 ra[2], rb[2];
    #pragma unroll
    for (int i = 0; i < 2; ++i) { ra[i] = *(const int4*)(gQ[i]); rb[i] = *(const int4*)(gK[i]); }

    for (int it = 0; it < 8; ++it) {
        __syncthreads();
        #pragma unroll
        for (int i = 0; i < 2; ++i) {
            *(int4*)((char*)sQ + offs[i]) = ra[i];
            *(int4*)((char*)sK + offs[i]) = rb[i];
        }
        __syncthreads();
        if (it < 7) {
            #pragma unroll
            for (int i = 0; i < 2; ++i) {
                ra[i] = *(const int4*)(gQ[i] + (it + 1) * 64);
                rb[i] = *(const int4*)(gK[i] + (it + 1) * 64);
            }
        }
        #pragma unroll
        for (int s = 0; s < 2; ++s) {
            bf16x8 aq[2], bk[2];
            #pragma unroll
            for (int m = 0; m < 2; ++m) {
                int r = wm * 32 + m * 16 + (lane & 15);
                int byte = r * 128 + s * 64 + ((lane >> 4) << 4);
                byte ^= (r & 7) << 4;
                aq[m] = *(const bf16x8*)((const char*)sQ + byte);
            }
            #pragma unroll
            for (int n = 0; n < 2; ++n) {
                int r = wn * 32 + n * 16 + (lane & 15);
                int byte = r * 128 + s * 64 + ((lane >> 4) << 4);
                byte ^= (r & 7) << 4;
                bk[n] = *(const bf16x8*)((const char*)sK + byte);
            }
            #pragma unroll
            for (int m = 0; m < 2; ++m)
                #pragma unroll
                for (int n = 0; n < 2; ++n)
                    acc[m][n] = __builtin_amdgcn_mfma_f32_16x16x32_bf16(
                        aq[m], bk[n], acc[m][n], 0, 0, 0);
        }
    }

    float* Sp = Spart + ((size_t)(bh * 8 + chunk) << 12);
    #pragma unroll
    for (int m = 0; m < 2; ++m)
        #pragma unroll
        for (int n = 0; n < 2; ++n)
            #pragma unroll
            for (int r4 = 0; r4 < 4; ++r4) {
                int r = wm * 32 + m * 16 + ((lane >> 4) << 2) + r4;
                int c = wn * 32 + n * 16 + (lane & 15);
                Sp[r * 64 + c] = acc[m][n][r4];
            }
}

// ---------------------------------------------------------------------------
// K4: combine partials + inline rsq from sumsq + scale + row softmax (fp32)
// ---------------------------------------------------------------------------
__global__ __launch_bounds__(64) void softmax_attn(
    const float* __restrict__ Spart, const float* __restrict__ sumsq,
    float* __restrict__ attn)
{
    const int bh = blockIdx.x;
    const int b = bh >> 3, h = bh & 7;
    const int r = threadIdx.x;
    __shared__ float srk[64];
    const float rq = 1.0f / fmaxf(sqrtf(sumsq[b * DIMC + h * 64 + r]), EPSN);
    srk[r] = 1.0f / fmaxf(sqrtf(sumsq[4096 + b * DIMC + h * 64 + r]), EPSN);
    __syncthreads();
    const float* Sp = Spart + ((size_t)(bh * 8) << 12) + r * 64;

    float row[64];
    #pragma unroll 8
    for (int c = 0; c < 64; ++c) {
        float s = 0.f;
        #pragma unroll
        for (int ch = 0; ch < 8; ++ch) s += Sp[((size_t)ch << 12) + c];
        row[c] = s * SCALE * rq * srk[c];
    }
    float mx = -1e30f;
    #pragma unroll 8
    for (int c = 0; c < 64; ++c) mx = fmaxf(mx, row[c]);
    float sum = 0.f;
    #pragma unroll 8
    for (int c = 0; c < 64; ++c) { row[c] = __expf(row[c] - mx); sum += row[c]; }
    const float inv = 1.0f / sum;
    float* A = attn + ((size_t)bh << 12) + r * 64;
    #pragma unroll 8
    for (int c = 0; c < 64; ++c) A[c] = row[c] * inv;
}

// ---------------------------------------------------------------------------
// K5: fold Wp through attn -> Wp2b bf16 [b][j][c]
// ---------------------------------------------------------------------------
__global__ __launch_bounds__(256) void build_wp2(
    const float* __restrict__ Wp, const float* __restrict__ attn,
    unsigned short* __restrict__ Wp2b)
{
    const int jt = blockIdx.x;
    const int h  = blockIdx.y;
    const int b  = blockIdx.z;

    __shared__ float sA[64][64];
    __shared__ float sW[64][64];

    const int t = threadIdx.x;
    {
        const float* A = attn + ((size_t)(b * 8 + h) << 12);
        for (int i = t * 4; i < 4096; i += 1024)
            *(float4*)&sA[0][i] = *(const float4*)(A + i);
    }
    {
        const int j  = t >> 2;
        const int c0 = (t & 3) * 16;
        #pragma unroll
        for (int i = 0; i < 4; ++i) {
            float4 w4 = *(const float4*)(Wp + (size_t)(jt * 64 + j) * DIMC + h * 64 + c0 + i * 4);
            sW[c0 + i * 4 + 0][j] = w4.x; sW[c0 + i * 4 + 1][j] = w4.y;
            sW[c0 + i * 4 + 2][j] = w4.z; sW[c0 + i * 4 + 3][j] = w4.w;
        }
    }
    __syncthreads();

    const int tx = t & 15, ty = t >> 4;
    float acc[4][4] = {};
    #pragma unroll 16
    for (int c = 0; c < 64; ++c) {
        float wf[4], af[4];
        #pragma unroll
        for (int i = 0; i < 4; ++i) { wf[i] = sW[c][ty * 4 + i]; af[i] = sA[c][tx * 4 + i]; }
        #pragma unroll
        for (int r = 0; r < 4; ++r)
            #pragma unroll
            for (int cc = 0; cc < 4; ++cc)
                acc[r][cc] = fmaf(wf[r], af[cc], acc[r][cc]);
    }

    unsigned short* O = Wp2b + ((size_t)b * DIMC + jt * 64 + ty * 4) * DIMC + h * 64 + tx * 4;
    #pragma unroll
    for (int r = 0; r < 4; ++r) {
        ushort4 o4;
        o4.x = f2bf(acc[r][0]); o4.y = f2bf(acc[r][1]);
        o4.z = f2bf(acc[r][2]); o4.w = f2bf(acc[r][3]);
        *(ushort4*)(O + (size_t)r * DIMC) = o4;
    }
}

// ---------------------------------------------------------------------------
// K6: final MFMA GEMM: out[b][j][n] = sum_c Wp2b[b][j][c] * vT[b][n][c]
// fp32 stores are 64B line-granular (lane&15 consecutive)
// ---------------------------------------------------------------------------
__global__ __launch_bounds__(256, 2) void final_mfma(
    const unsigned short* __restrict__ Wp2b, const unsigned short* __restrict__ vT,
    float* __restrict__ out)
{
    const int b  = blockIdx.z;
    const int j0 = blockIdx.y * 64;
    const int n0 = blockIdx.x * 128;
    const unsigned short* A = Wp2b + (size_t)b * DIMC * DIMC;
    const unsigned short* B = vT + (size_t)b * HW * DIMC;

    __shared__ unsigned short sA[64 * 64];
    __shared__ unsigned short sB[128 * 64];

    const int t = threadIdx.x, lane = t & 63, w = t >> 6;
    const int wm = w >> 1, wn = w & 1;

    f32x4 zero = {0.f, 0.f, 0.f, 0.f};
    f32x4 acc[2][4];
    #pragma unroll
    for (int m = 0; m < 2; ++m)
        #pragma unroll
        for (int n = 0; n < 4; ++n) acc[m][n] = zero;

    int offA[2], offB[4];
    const unsigned short* gA[2];
    const unsigned short* gB[4];
    #pragma unroll
    for (int i = 0; i < 2; ++i) {
        int ch = t + i * 256, r = ch >> 3, sl = ch & 7;
        offA[i] = r * 128 + ((sl ^ (r & 7)) << 4);
        gA[i] = A + (size_t)(j0 + r) * DIMC + sl * 8;
    }
    #pragma unroll
    for (int i = 0; i < 4; ++i) {
        int ch = t + i * 256, r = ch >> 3, sl = ch & 7;
        offB[i] = r * 128 + ((sl ^ (r & 7)) << 4);
        gB[i] = B + (size_t)(n0 + r) * DIMC + sl * 8;
    }

    int4 ra[2], rb[4];
    #pragma unroll
    for (int i = 0; i < 2; ++i) ra[i] = *(const int4*)(gA[i]);
    #pragma unroll
    for (int i = 0; i < 4; ++i) rb[i] = *(const int4*)(gB[i]);

    for (int c0 = 0; c0 < DIMC; c0 += 64) {
        __syncthreads();
        #pragma unroll
        for (int i = 0; i < 2; ++i) *(int4*)((char*)sA + offA[i]) = ra[i];
        #pragma unroll
        for (int i = 0; i < 4; ++i) *(int4*)((char*)sB + offB[i]) = rb[i];
        __syncthreads();
        if (c0 + 64 < DIMC) {
            #pragma unroll
            for (int i = 0; i < 2; ++i) ra[i] = *(const int4*)(gA[i] + c0 + 64);
            #pragma unroll
            for (int i = 0; i < 4; ++i) rb[i] = *(const int4*)(gB[i] + c0 + 64);
        }
        #pragma unroll
        for (int s = 0; s < 2; ++s) {
            bf16x8 af[2], bfr[4];
            #pragma unroll
            for (int m = 0; m < 2; ++m) {
                int r = wm * 32 + m * 16 + (lane & 15);
                int byte = r * 128 + s * 64 + ((lane >> 4) << 4);
                byte ^= (r & 7) << 4;
                af[m] = *(const bf16x8*)((const char*)sA + byte);
            }
            #pragma unroll
            for (int n = 0; n < 4; ++n) {
                int r = wn * 64 + n * 16 + (lane & 15);
                int byte = r * 128 + s * 64 + ((lane >> 4) << 4);
                byte ^= (r & 7) << 4;
                bfr[n] = *(const bf16x8*)((const char*)sB + byte);
            }
            #pragma unroll
            for (int m = 0; m < 2; ++m)
                #pragma unroll
                for (int n = 0; n < 4; ++n)
                    acc[m][n] = __builtin_amdgcn_mfma_f32_16x16x32_bf16(
                        af[m], bfr[n], acc[m][n], 0, 0, 0);
        }
    }

    #pragma unroll
    for (int m = 0; m < 2; ++m)
        #pragma unroll
        for (int r4 = 0; r4 < 4; ++r4) {
            int j = j0 + wm * 32 + m * 16 + ((lane >> 4) << 2) + r4;
            size_t rowbase = ((size_t)b * DIMC + j) * HW + n0 + wn * 64 + (lane & 15);
            #pragma unroll
            for (int n = 0; n < 4; ++n)
                out[rowbase + n * 16] = acc[m][n][r4];
        }
}

// ---------------------------------------------------------------------------
// Workspace (bytes):
//   xT    @ 0           33,554,432
//   q     @ 33554432    33,554,432
//   k     @ 67108864    33,554,432
//   vT    @ 100663296   33,554,432
//   Wb    @ 134217728    1,572,864
//   Wp2b  @ 135790592    4,194,304
//   sumsq @ 139984896       32,768   (q rows then k rows, zeroed each call)
//   Spart @ 140017664    8,388,608
//   attn  @ 148406272    1,048,576
// ---------------------------------------------------------------------------
extern "C" void kernel_launch(void* const* d_in, const int* in_sizes, int n_in,
                              void* d_out, int out_size, void* d_ws, size_t ws_size,
                              hipStream_t stream)
{
    const float* x    = (const float*)d_in[0];
    const float* mask = (const float*)d_in[1];
    const float* Wq   = (const float*)d_in[2];
    const float* Wk   = (const float*)d_in[3];
    const float* Wv   = (const float*)d_in[4];
    const float* Wp   = (const float*)d_in[5];
    float* out = (float*)d_out;
    char* wsb = (char*)d_ws;

    unsigned short* xT   = (unsigned short*)(wsb + 0);
    unsigned short* q    = (unsigned short*)(wsb + 33554432);
    unsigned short* k    = (unsigned short*)(wsb + 67108864);
    unsigned short* vT   = (unsigned short*)(wsb + 100663296);
    unsigned short* Wb   = (unsigned short*)(wsb + 134217728);
    unsigned short* Wp2b = (unsigned short*)(wsb + 135790592);
    float* sumsq = (float*)(wsb + 139984896);
    float* Spart = (float*)(wsb + 140017664);
    float* attn  = (float*)(wsb + 148406272);

    hipMemsetAsync(sumsq, 0, 2 * 4096 * sizeof(float), stream);

    convert_w    <<<768,              256, 0, stream>>>(Wq, Wk, Wv, Wb);
    transpose_x  <<<dim3(64, 8, 8),   256, 0, stream>>>(x, xT);
    qkv_mfma     <<<dim3(32, 8, 24),  256, 0, stream>>>(Wb, xT, mask, q, k, vT, sumsq);
    attn_mfma    <<<dim3(64, 8),      256, 0, stream>>>(q, k, Spart);
    softmax_attn <<<64,                64, 0, stream>>>(Spart, sumsq, attn);
    build_wp2    <<<dim3(8, 8, 8),    256, 0, stream>>>(Wp, attn, Wp2b);
    final_mfma   <<<dim3(32, 8, 8),   256, 0, stream>>>(Wp2b, vT, out);
}

// Round 6
// 209.165 us; speedup vs baseline: 2.5869x; 2.5869x over previous
//
#include <hip/hip_runtime.h>
#include <math.h>

#define DIMC 512
#define HW 4096
#define SCALE 0.125f
#define EPSN 1e-12f

typedef __attribute__((ext_vector_type(8))) short bf16x8;
typedef __attribute__((ext_vector_type(4))) float f32x4;

__device__ __forceinline__ unsigned short f2bf(float f) {
    union { float f; unsigned int u; } v; v.f = f;
    unsigned int u = v.u;
    return (unsigned short)((u + 0x7fffu + ((u >> 16) & 1u)) >> 16);
}

union Pack8 { int4 v; unsigned short u[8]; };

// async global->LDS, 16B per lane, wave-uniform LDS base (HW: base + lane*16)
__device__ __forceinline__ void gload_lds16(const unsigned short* src, char* ldst) {
    __builtin_amdgcn_global_load_lds(
        (const __attribute__((address_space(1))) void*)src,
        (__attribute__((address_space(3))) void*)ldst, 16, 0, 0);
}

// ---------------------------------------------------------------------------
// P1: convert Wq,Wk,Wv fp32 -> Wb bf16 [3][512][512]
// ---------------------------------------------------------------------------
__global__ __launch_bounds__(256) void convert_w(
    const float* __restrict__ Wq, const float* __restrict__ Wk,
    const float* __restrict__ Wv, unsigned short* __restrict__ Wb)
{
    int i = (blockIdx.x * 256 + threadIdx.x) * 4;
    int m = i >> 18;
    int off = i & 262143;
    const float* s = (m == 0) ? Wq : (m == 1) ? Wk : Wv;
    float4 v4 = *(const float4*)(s + off);
    ushort4 o;
    o.x = f2bf(v4.x); o.y = f2bf(v4.y); o.z = f2bf(v4.z); o.w = f2bf(v4.w);
    *(ushort4*)(Wb + i) = o;
}

// ---------------------------------------------------------------------------
// P2: transpose+convert x[b][c][n] fp32 -> xT[b][n][c] bf16
// ---------------------------------------------------------------------------
__global__ __launch_bounds__(256) void transpose_x(
    const float* __restrict__ x, unsigned short* __restrict__ xT)
{
    const int b  = blockIdx.z;
    const int c0 = blockIdx.y * 64;
    const int n0 = blockIdx.x * 64;
    __shared__ unsigned short sT[64][65];
    const int t = threadIdx.x;
    #pragma unroll
    for (int i = 0; i < 4; ++i) {
        int ch = t + i * 256;
        int r = ch >> 4, col4 = (ch & 15) * 4;
        float4 v4 = *(const float4*)(x + ((size_t)b * DIMC + c0 + r) * HW + n0 + col4);
        sT[r][col4 + 0] = f2bf(v4.x); sT[r][col4 + 1] = f2bf(v4.y);
        sT[r][col4 + 2] = f2bf(v4.z); sT[r][col4 + 3] = f2bf(v4.w);
    }
    __syncthreads();
    #pragma unroll
    for (int i = 0; i < 2; ++i) {
        int ch = t + i * 256;
        int n = ch >> 3, cc = (ch & 7) * 8;
        Pack8 pk;
        #pragma unroll
        for (int e = 0; e < 8; ++e) pk.u[e] = sT[cc + e][n];
        *(int4*)(xT + ((size_t)b * HW + n0 + n) * DIMC + c0 + cc) = pk.v;
    }
}

// ---------------------------------------------------------------------------
// K1: MFMA QKV projection (split per output; which = blockIdx.z>>3).
// R6 change: staging via global_load_lds (async, no VGPR round-trip) ->
// removes the per-iteration int4 prefetch registers that were spilling to
// scratch (R3/R4/R5: 0.7-1.3 GB phantom HBM writes). Double-buffered LDS,
// m97 2-barrier schedule. Swizzle: linear LDS dest + pre-swizzled global
// source col = ((lane&7)^(lane>>3))*8; read side unchanged.
// BM=64(j) x BN=128(n), BK=64, 4 waves (2x2), acc 2x4.
// ---------------------------------------------------------------------------
__global__ __launch_bounds__(256) void qkv_mfma(
    const unsigned short* __restrict__ Wb, const unsigned short* __restrict__ xT,
    const float* __restrict__ mask,
    unsigned short* __restrict__ q, unsigned short* __restrict__ k,
    unsigned short* __restrict__ vT, float* __restrict__ sumsq)
{
    const int which = blockIdx.z >> 3;   // 0=q,1=k,2=v
    const int b     = blockIdx.z & 7;
    const int j0 = blockIdx.y * 64;
    const int n0 = blockIdx.x * 128;
    const unsigned short* A = Wb + (size_t)which * 262144 + (size_t)j0 * DIMC;
    const unsigned short* B = xT + (size_t)b * HW * DIMC + (size_t)n0 * DIMC;

    // double buffer: stride 24576 (A 8KB @ 0, B 16KB @ 8192); total 48KB
    __shared__ __align__(16) char sm[49152];

    const int t = threadIdx.x, lane = t & 63, w = t >> 6;
    const int wm = w >> 1, wn = w & 1;
    const int rsub = lane >> 3;                      // row within 8-row group
    const int srccol = ((lane & 7) ^ rsub) << 3;     // pre-swizzled src col (elems)

    f32x4 zero = {0.f, 0.f, 0.f, 0.f};
    f32x4 acc[2][4];
    #pragma unroll
    for (int m = 0; m < 2; ++m)
        #pragma unroll
        for (int n = 0; n < 4; ++n) acc[m][n] = zero;

    #define STAGE_QKV(buf, c0)                                                  \
        {                                                                       \
            char* dst = sm + (buf) * 24576;                                     \
            _Pragma("unroll")                                                   \
            for (int i = 0; i < 2; ++i) {                                       \
                int ii = w * 2 + i;                                             \
                gload_lds16(A + (size_t)(ii * 8 + rsub) * DIMC + (c0) + srccol, \
                            dst + ii * 1024);                                   \
            }                                                                   \
            _Pragma("unroll")                                                   \
            for (int i = 0; i < 4; ++i) {                                       \
                int ii = w * 4 + i;                                             \
                gload_lds16(B + (size_t)(ii * 8 + rsub) * DIMC + (c0) + srccol, \
                            dst + 8192 + ii * 1024);                            \
            }                                                                   \
        }

    STAGE_QKV(0, 0);
    int cur = 0;
    for (int c0 = 0; c0 < DIMC; c0 += 64) {
        __syncthreads();                       // vmcnt drain: buf[cur] ready
        if (c0 + 64 < DIMC) STAGE_QKV(cur ^ 1, c0 + 64);
        const char* sA = sm + cur * 24576;
        const char* sB = sA + 8192;
        #pragma unroll
        for (int s = 0; s < 2; ++s) {
            bf16x8 af[2], bfr[4];
            #pragma unroll
            for (int m = 0; m < 2; ++m) {
                int r = wm * 32 + m * 16 + (lane & 15);
                int byte = r * 128 + s * 64 + ((lane >> 4) << 4);
                byte ^= (r & 7) << 4;
                af[m] = *(const bf16x8*)(sA + byte);
            }
            #pragma unroll
            for (int n = 0; n < 4; ++n) {
                int r = wn * 64 + n * 16 + (lane & 15);
                int byte = r * 128 + s * 64 + ((lane >> 4) << 4);
                byte ^= (r & 7) << 4;
                bfr[n] = *(const bf16x8*)(sB + byte);
            }
            #pragma unroll
            for (int m = 0; m < 2; ++m)
                #pragma unroll
                for (int n = 0; n < 4; ++n)
                    acc[m][n] = __builtin_amdgcn_mfma_f32_16x16x32_bf16(
                        af[m], bfr[n], acc[m][n], 0, 0, 0);
        }
        cur ^= 1;
    }
    #undef STAGE_QKV

    unsigned short* st = (unsigned short*)sm;

    if (which < 2) {
        float mv[4];
        #pragma unroll
        for (int n = 0; n < 4; ++n)
            mv[n] = mask[(size_t)b * HW + n0 + wn * 64 + n * 16 + (lane & 15)];
        #pragma unroll
        for (int m = 0; m < 2; ++m)
            #pragma unroll
            for (int n = 0; n < 4; ++n)
                #pragma unroll
                for (int r4 = 0; r4 < 4; ++r4)
                    acc[m][n][r4] *= mv[n];
        #pragma unroll
        for (int m = 0; m < 2; ++m)
            #pragma unroll
            for (int r4 = 0; r4 < 4; ++r4) {
                float s = 0.f;
                #pragma unroll
                for (int n = 0; n < 4; ++n)
                    s = fmaf(acc[m][n][r4], acc[m][n][r4], s);
                s += __shfl_xor(s, 8, 16);
                s += __shfl_xor(s, 4, 16);
                s += __shfl_xor(s, 2, 16);
                s += __shfl_xor(s, 1, 16);
                if ((lane & 15) == 0) {
                    int j = j0 + wm * 32 + m * 16 + ((lane >> 4) << 2) + r4;
                    atomicAdd(&sumsq[which * 4096 + b * DIMC + j], s);
                }
            }

        unsigned short* outp = which ? k : q;
        __syncthreads();
        #pragma unroll
        for (int m = 0; m < 2; ++m)
            #pragma unroll
            for (int n = 0; n < 4; ++n)
                #pragma unroll
                for (int r4 = 0; r4 < 4; ++r4) {
                    int jl = wm * 32 + m * 16 + ((lane >> 4) << 2) + r4;
                    int nl = wn * 64 + n * 16 + (lane & 15);
                    st[jl * 136 + nl] = f2bf(acc[m][n][r4]);
                }
        __syncthreads();
        #pragma unroll
        for (int it = 0; it < 4; ++it) {
            int idx = t + it * 256, jl = idx >> 4, l16 = idx & 15;
            int4 pv = *(int4*)(sm + jl * 272 + l16 * 16);
            *(int4*)(outp + ((size_t)b * DIMC + j0 + jl) * HW + n0 + l16 * 8) = pv;
        }
    } else {
        __syncthreads();
        #pragma unroll
        for (int m = 0; m < 2; ++m)
            #pragma unroll
            for (int n = 0; n < 4; ++n)
                #pragma unroll
                for (int r4 = 0; r4 < 4; ++r4) {
                    int jl = wm * 32 + m * 16 + ((lane >> 4) << 2) + r4;
                    int nl = wn * 64 + n * 16 + (lane & 15);
                    st[nl * 72 + jl] = f2bf(acc[m][n][r4]);
                }
        __syncthreads();
        #pragma unroll
        for (int it = 0; it < 4; ++it) {
            int idx = t + it * 256, nl = idx >> 3, c8 = idx & 7;
            int4 pv = *(int4*)(sm + nl * 144 + c8 * 16);
            *(int4*)(vT + ((size_t)b * HW + n0 + nl) * DIMC + j0 + c8 * 8) = pv;
        }
    }
}

// ---------------------------------------------------------------------------
// K3: MFMA attention logits (NT GEMM). Unchanged (minor cost).
// ---------------------------------------------------------------------------
__global__ __launch_bounds__(256) void attn_mfma(
    const unsigned short* __restrict__ q, const unsigned short* __restrict__ k,
    float* __restrict__ Spart)
{
    const int bh = blockIdx.x;
    const int chunk = blockIdx.y;
    const unsigned short* Q = q + (size_t)bh * 64 * HW;
    const unsigned short* K = k + (size_t)bh * 64 * HW;

    __shared__ unsigned short sQ[64 * 64];
    __shared__ unsigned short sK[64 * 64];

    const int t = threadIdx.x, lane = t & 63, w = t >> 6;
    const int wm = w >> 1, wn = w & 1;

    f32x4 zero = {0.f, 0.f, 0.f, 0.f};
    f32x4 acc[2][2];
    #pragma unroll
    for (int m = 0; m < 2; ++m)
        #pragma unroll
        for (int n = 0; n < 2; ++n) acc[m][n] = zero;

    int offs[2];
    const unsigned short* gQ[2];
    const unsigned short* gK[2];
    const int nb = chunk * 512;
    #pragma unroll
    for (int i = 0; i < 2; ++i) {
        int ch = t + i * 256, r = ch >> 3, sl = ch & 7;
        offs[i] = r * 128 + ((sl ^ (r & 7)) << 4);
        gQ[i] = Q + (size_t)r * HW + nb + sl * 8;
        gK[i] = K + (size_t)r * HW + nb + sl * 8;
    }

    int4 ra[2], rb[2];
    #pragma unroll
    for (int i = 0; i < 2; ++i) { ra[i] = *(const int4*)(gQ[i]); rb[i] = *(const int4*)(gK[i]); }

    for (int it = 0; it < 8; ++it) {
        __syncthreads();
        #pragma unroll
        for (int i = 0; i < 2; ++i) {
            *(int4*)((char*)sQ + offs[i]) = ra[i];
            *(int4*)((char*)sK + offs[i]) = rb[i];
        }
        __syncthreads();
        if (it < 7) {
            #pragma unroll
            for (int i = 0; i < 2; ++i) {
                ra[i] = *(const int4*)(gQ[i] + (it + 1) * 64);
                rb[i] = *(const int4*)(gK[i] + (it + 1) * 64);
            }
        }
        #pragma unroll
        for (int s = 0; s < 2; ++s) {
            bf16x8 aq[2], bk[2];
            #pragma unroll
            for (int m = 0; m < 2; ++m) {
                int r = wm * 32 + m * 16 + (lane & 15);
                int byte = r * 128 + s * 64 + ((lane >> 4) << 4);
                byte ^= (r & 7) << 4;
                aq[m] = *(const bf16x8*)((const char*)sQ + byte);
            }
            #pragma unroll
            for (int n = 0; n < 2; ++n) {
                int r = wn * 32 + n * 16 + (lane & 15);
                int byte = r * 128 + s * 64 + ((lane >> 4) << 4);
                byte ^= (r & 7) << 4;
                bk[n] = *(const bf16x8*)((const char*)sK + byte);
            }
            #pragma unroll
            for (int m = 0; m < 2; ++m)
                #pragma unroll
                for (int n = 0; n < 2; ++n)
                    acc[m][n] = __builtin_amdgcn_mfma_f32_16x16x32_bf16(
                        aq[m], bk[n], acc[m][n], 0, 0, 0);
        }
    }

    float* Sp = Spart + ((size_t)(bh * 8 + chunk) << 12);
    #pragma unroll
    for (int m = 0; m < 2; ++m)
        #pragma unroll
        for (int n = 0; n < 2; ++n)
            #pragma unroll
            for (int r4 = 0; r4 < 4; ++r4) {
                int r = wm * 32 + m * 16 + ((lane >> 4) << 2) + r4;
                int c = wn * 32 + n * 16 + (lane & 15);
                Sp[r * 64 + c] = acc[m][n][r4];
            }
}

// ---------------------------------------------------------------------------
// K4: combine partials + inline rsq from sumsq + scale + row softmax (fp32)
// ---------------------------------------------------------------------------
__global__ __launch_bounds__(64) void softmax_attn(
    const float* __restrict__ Spart, const float* __restrict__ sumsq,
    float* __restrict__ attn)
{
    const int bh = blockIdx.x;
    const int b = bh >> 3, h = bh & 7;
    const int r = threadIdx.x;
    __shared__ float srk[64];
    const float rq = 1.0f / fmaxf(sqrtf(sumsq[b * DIMC + h * 64 + r]), EPSN);
    srk[r] = 1.0f / fmaxf(sqrtf(sumsq[4096 + b * DIMC + h * 64 + r]), EPSN);
    __syncthreads();
    const float* Sp = Spart + ((size_t)(bh * 8) << 12) + r * 64;

    float row[64];
    #pragma unroll 8
    for (int c = 0; c < 64; ++c) {
        float s = 0.f;
        #pragma unroll
        for (int ch = 0; ch < 8; ++ch) s += Sp[((size_t)ch << 12) + c];
        row[c] = s * SCALE * rq * srk[c];
    }
    float mx = -1e30f;
    #pragma unroll 8
    for (int c = 0; c < 64; ++c) mx = fmaxf(mx, row[c]);
    float sum = 0.f;
    #pragma unroll 8
    for (int c = 0; c < 64; ++c) { row[c] = __expf(row[c] - mx); sum += row[c]; }
    const float inv = 1.0f / sum;
    float* A = attn + ((size_t)bh << 12) + r * 64;
    #pragma unroll 8
    for (int c = 0; c < 64; ++c) A[c] = row[c] * inv;
}

// ---------------------------------------------------------------------------
// K5: fold Wp through attn -> Wp2b bf16 [b][j][c]
// ---------------------------------------------------------------------------
__global__ __launch_bounds__(256) void build_wp2(
    const float* __restrict__ Wp, const float* __restrict__ attn,
    unsigned short* __restrict__ Wp2b)
{
    const int jt = blockIdx.x;
    const int h  = blockIdx.y;
    const int b  = blockIdx.z;

    __shared__ float sA[64][64];
    __shared__ float sW[64][64];

    const int t = threadIdx.x;
    {
        const float* A = attn + ((size_t)(b * 8 + h) << 12);
        for (int i = t * 4; i < 4096; i += 1024)
            *(float4*)&sA[0][i] = *(const float4*)(A + i);
    }
    {
        const int j  = t >> 2;
        const int c0 = (t & 3) * 16;
        #pragma unroll
        for (int i = 0; i < 4; ++i) {
            float4 w4 = *(const float4*)(Wp + (size_t)(jt * 64 + j) * DIMC + h * 64 + c0 + i * 4);
            sW[c0 + i * 4 + 0][j] = w4.x; sW[c0 + i * 4 + 1][j] = w4.y;
            sW[c0 + i * 4 + 2][j] = w4.z; sW[c0 + i * 4 + 3][j] = w4.w;
        }
    }
    __syncthreads();

    const int tx = t & 15, ty = t >> 4;
    float acc[4][4] = {};
    #pragma unroll 16
    for (int c = 0; c < 64; ++c) {
        float wf[4], af[4];
        #pragma unroll
        for (int i = 0; i < 4; ++i) { wf[i] = sW[c][ty * 4 + i]; af[i] = sA[c][tx * 4 + i]; }
        #pragma unroll
        for (int r = 0; r < 4; ++r)
            #pragma unroll
            for (int cc = 0; cc < 4; ++cc)
                acc[r][cc] = fmaf(wf[r], af[cc], acc[r][cc]);
    }

    unsigned short* O = Wp2b + ((size_t)b * DIMC + jt * 64 + ty * 4) * DIMC + h * 64 + tx * 4;
    #pragma unroll
    for (int r = 0; r < 4; ++r) {
        ushort4 o4;
        o4.x = f2bf(acc[r][0]); o4.y = f2bf(acc[r][1]);
        o4.z = f2bf(acc[r][2]); o4.w = f2bf(acc[r][3]);
        *(ushort4*)(O + (size_t)r * DIMC) = o4;
    }
}

// ---------------------------------------------------------------------------
// K6: final MFMA GEMM: out[b][j][n] = sum_c Wp2b[b][j][c] * vT[b][n][c]
// R6: same global_load_lds staging as qkv_mfma. fp32 stores line-granular.
// ---------------------------------------------------------------------------
__global__ __launch_bounds__(256) void final_mfma(
    const unsigned short* __restrict__ Wp2b, const unsigned short* __restrict__ vT,
    float* __restrict__ out)
{
    const int b  = blockIdx.z;
    const int j0 = blockIdx.y * 64;
    const int n0 = blockIdx.x * 128;
    const unsigned short* A = Wp2b + (size_t)b * DIMC * DIMC + (size_t)j0 * DIMC;
    const unsigned short* B = vT + (size_t)b * HW * DIMC + (size_t)n0 * DIMC;

    __shared__ __align__(16) char sm[49152];

    const int t = threadIdx.x, lane = t & 63, w = t >> 6;
    const int wm = w >> 1, wn = w & 1;
    const int rsub = lane >> 3;
    const int srccol = ((lane & 7) ^ rsub) << 3;

    f32x4 zero = {0.f, 0.f, 0.f, 0.f};
    f32x4 acc[2][4];
    #pragma unroll
    for (int m = 0; m < 2; ++m)
        #pragma unroll
        for (int n = 0; n < 4; ++n) acc[m][n] = zero;

    #define STAGE_FIN(buf, c0)                                                  \
        {                                                                       \
            char* dst = sm + (buf) * 24576;                                     \
            _Pragma("unroll")                                                   \
            for (int i = 0; i < 2; ++i) {                                       \
                int ii = w * 2 + i;                                             \
                gload_lds16(A + (size_t)(ii * 8 + rsub) * DIMC + (c0) + srccol, \
                            dst + ii * 1024);                                   \
            }                                                                   \
            _Pragma("unroll")                                                   \
            for (int i = 0; i < 4; ++i) {                                       \
                int ii = w * 4 + i;                                             \
                gload_lds16(B + (size_t)(ii * 8 + rsub) * DIMC + (c0) + srccol, \
                            dst + 8192 + ii * 1024);                            \
            }                                                                   \
        }

    STAGE_FIN(0, 0);
    int cur = 0;
    for (int c0 = 0; c0 < DIMC; c0 += 64) {
        __syncthreads();
        if (c0 + 64 < DIMC) STAGE_FIN(cur ^ 1, c0 + 64);
        const char* sA = sm + cur * 24576;
        const char* sB = sA + 8192;
        #pragma unroll
        for (int s = 0; s < 2; ++s) {
            bf16x8 af[2], bfr[4];
            #pragma unroll
            for (int m = 0; m < 2; ++m) {
                int r = wm * 32 + m * 16 + (lane & 15);
                int byte = r * 128 + s * 64 + ((lane >> 4) << 4);
                byte ^= (r & 7) << 4;
                af[m] = *(const bf16x8*)(sA + byte);
            }
            #pragma unroll
            for (int n = 0; n < 4; ++n) {
                int r = wn * 64 + n * 16 + (lane & 15);
                int byte = r * 128 + s * 64 + ((lane >> 4) << 4);
                byte ^= (r & 7) << 4;
                bfr[n] = *(const bf16x8*)(sB + byte);
            }
            #pragma unroll
            for (int m = 0; m < 2; ++m)
                #pragma unroll
                for (int n = 0; n < 4; ++n)
                    acc[m][n] = __builtin_amdgcn_mfma_f32_16x16x32_bf16(
                        af[m], bfr[n], acc[m][n], 0, 0, 0);
        }
        cur ^= 1;
    }
    #undef STAGE_FIN

    #pragma unroll
    for (int m = 0; m < 2; ++m)
        #pragma unroll
        for (int r4 = 0; r4 < 4; ++r4) {
            int j = j0 + wm * 32 + m * 16 + ((lane >> 4) << 2) + r4;
            size_t rowbase = ((size_t)b * DIMC + j) * HW + n0 + wn * 64 + (lane & 15);
            #pragma unroll
            for (int n = 0; n < 4; ++n)
                out[rowbase + n * 16] = acc[m][n][r4];
        }
}

// ---------------------------------------------------------------------------
// Workspace (bytes):
//   xT    @ 0           33,554,432
//   q     @ 33554432    33,554,432
//   k     @ 67108864    33,554,432
//   vT    @ 100663296   33,554,432
//   Wb    @ 134217728    1,572,864
//   Wp2b  @ 135790592    4,194,304
//   sumsq @ 139984896       32,768   (q rows then k rows, zeroed each call)
//   Spart @ 140017664    8,388,608
//   attn  @ 148406272    1,048,576
// ---------------------------------------------------------------------------
extern "C" void kernel_launch(void* const* d_in, const int* in_sizes, int n_in,
                              void* d_out, int out_size, void* d_ws, size_t ws_size,
                              hipStream_t stream)
{
    const float* x    = (const float*)d_in[0];
    const float* mask = (const float*)d_in[1];
    const float* Wq   = (const float*)d_in[2];
    const float* Wk   = (const float*)d_in[3];
    const float* Wv   = (const float*)d_in[4];
    const float* Wp   = (const float*)d_in[5];
    float* out = (float*)d_out;
    char* wsb = (char*)d_ws;

    unsigned short* xT   = (unsigned short*)(wsb + 0);
    unsigned short* q    = (unsigned short*)(wsb + 33554432);
    unsigned short* k    = (unsigned short*)(wsb + 67108864);
    unsigned short* vT   = (unsigned short*)(wsb + 100663296);
    unsigned short* Wb   = (unsigned short*)(wsb + 134217728);
    unsigned short* Wp2b = (unsigned short*)(wsb + 135790592);
    float* sumsq = (float*)(wsb + 139984896);
    float* Spart = (float*)(wsb + 140017664);
    float* attn  = (float*)(wsb + 148406272);

    hipMemsetAsync(sumsq, 0, 2 * 4096 * sizeof(float), stream);

    convert_w    <<<768,              256, 0, stream>>>(Wq, Wk, Wv, Wb);
    transpose_x  <<<dim3(64, 8, 8),   256, 0, stream>>>(x, xT);
    qkv_mfma     <<<dim3(32, 8, 24),  256, 0, stream>>>(Wb, xT, mask, q, k, vT, sumsq);
    attn_mfma    <<<dim3(64, 8),      256, 0, stream>>>(q, k, Spart);
    softmax_attn <<<64,                64, 0, stream>>>(Spart, sumsq, attn);
    build_wp2    <<<dim3(8, 8, 8),    256, 0, stream>>>(Wp, attn, Wp2b);
    final_mfma   <<<dim3(32, 8, 8),   256, 0, stream>>>(Wp2b, vT, out);
}

// Round 7
// 178.834 us; speedup vs baseline: 3.0256x; 1.1696x over previous
//
#include <hip/hip_runtime.h>
#include <math.h>

#define DIMC 512
#define HW 4096
#define SCALE 0.125f
#define EPSN 1e-12f

typedef __attribute__((ext_vector_type(8))) short bf16x8;
typedef __attribute__((ext_vector_type(4))) float f32x4;

__device__ __forceinline__ unsigned short f2bf(float f) {
    union { float f; unsigned int u; } v; v.f = f;
    unsigned int u = v.u;
    return (unsigned short)((u + 0x7fffu + ((u >> 16) & 1u)) >> 16);
}

union Pack8 { int4 v; unsigned short u[8]; };

// async global->LDS, 16B per lane, wave-uniform LDS base (HW: base + lane*16)
__device__ __forceinline__ void gload_lds16(const unsigned short* src, char* ldst) {
    __builtin_amdgcn_global_load_lds(
        (const __attribute__((address_space(1))) void*)src,
        (__attribute__((address_space(3))) void*)ldst, 16, 0, 0);
}

// ---------------------------------------------------------------------------
// P1: convert Wq,Wk,Wv fp32 -> Wb bf16 [3][512][512]
// ---------------------------------------------------------------------------
__global__ __launch_bounds__(256) void convert_w(
    const float* __restrict__ Wq, const float* __restrict__ Wk,
    const float* __restrict__ Wv, unsigned short* __restrict__ Wb)
{
    int i = (blockIdx.x * 256 + threadIdx.x) * 4;
    int m = i >> 18;
    int off = i & 262143;
    const float* s = (m == 0) ? Wq : (m == 1) ? Wk : Wv;
    float4 v4 = *(const float4*)(s + off);
    ushort4 o;
    o.x = f2bf(v4.x); o.y = f2bf(v4.y); o.z = f2bf(v4.z); o.w = f2bf(v4.w);
    *(ushort4*)(Wb + i) = o;
}

// ---------------------------------------------------------------------------
// P2: transpose+convert x[b][c][n] fp32 -> xT[b][n][c] bf16
// ---------------------------------------------------------------------------
__global__ __launch_bounds__(256) void transpose_x(
    const float* __restrict__ x, unsigned short* __restrict__ xT)
{
    const int b  = blockIdx.z;
    const int c0 = blockIdx.y * 64;
    const int n0 = blockIdx.x * 64;
    __shared__ unsigned short sT[64][65];
    const int t = threadIdx.x;
    #pragma unroll
    for (int i = 0; i < 4; ++i) {
        int ch = t + i * 256;
        int r = ch >> 4, col4 = (ch & 15) * 4;
        float4 v4 = *(const float4*)(x + ((size_t)b * DIMC + c0 + r) * HW + n0 + col4);
        sT[r][col4 + 0] = f2bf(v4.x); sT[r][col4 + 1] = f2bf(v4.y);
        sT[r][col4 + 2] = f2bf(v4.z); sT[r][col4 + 3] = f2bf(v4.w);
    }
    __syncthreads();
    #pragma unroll
    for (int i = 0; i < 2; ++i) {
        int ch = t + i * 256;
        int n = ch >> 3, cc = (ch & 7) * 8;
        Pack8 pk;
        #pragma unroll
        for (int e = 0; e < 8; ++e) pk.u[e] = sT[cc + e][n];
        *(int4*)(xT + ((size_t)b * HW + n0 + n) * DIMC + c0 + cc) = pk.v;
    }
}

// ---------------------------------------------------------------------------
// K1: MFMA QKV projection. R7: q and k FUSED in one block type (share the B
// tile; safe now that global_load_lds staging removed the spill-prone
// prefetch registers). which = blockIdx.z>>3: 0 = q+k fused, 1 = v.
// BM=64(j) x BN=128(n), BK=64, 4 waves (2x2).
// LDS per buffer (stride 32768): Aq @0 (8KB), Ak @8192, B @16384 (16KB).
// ---------------------------------------------------------------------------
__global__ __launch_bounds__(256) void qkv_mfma(
    const unsigned short* __restrict__ Wb, const unsigned short* __restrict__ xT,
    const float* __restrict__ mask,
    unsigned short* __restrict__ q, unsigned short* __restrict__ k,
    unsigned short* __restrict__ vT, float* __restrict__ sumsq)
{
    const int which = blockIdx.z >> 3;   // 0 = q+k, 1 = v
    const int b     = blockIdx.z & 7;
    const int j0 = blockIdx.y * 64;
    const int n0 = blockIdx.x * 128;
    const unsigned short* B = xT + (size_t)b * HW * DIMC + (size_t)n0 * DIMC;

    __shared__ __align__(16) char sm[65536];   // 2 x 32KB buffers

    const int t = threadIdx.x, lane = t & 63, w = t >> 6;
    const int wm = w >> 1, wn = w & 1;
    const int rsub = lane >> 3;                      // row within 8-row group
    const int srccol = ((lane & 7) ^ rsub) << 3;     // pre-swizzled src col

    f32x4 zero = {0.f, 0.f, 0.f, 0.f};
    unsigned short* st = (unsigned short*)sm;

    if (which == 0) {
        // ---------------- fused q + k ----------------
        const unsigned short* Aq = Wb + (size_t)j0 * DIMC;
        const unsigned short* Ak = Wb + 262144 + (size_t)j0 * DIMC;

        f32x4 accQ[2][4], accK[2][4];
        #pragma unroll
        for (int m = 0; m < 2; ++m)
            #pragma unroll
            for (int n = 0; n < 4; ++n) { accQ[m][n] = zero; accK[m][n] = zero; }

        #define STAGE_QK(buf, c0)                                                   \
            {                                                                       \
                char* dst = sm + (buf) * 32768;                                     \
                _Pragma("unroll")                                                   \
                for (int i = 0; i < 2; ++i) {                                       \
                    int ii = w * 2 + i;                                             \
                    gload_lds16(Aq + (size_t)(ii * 8 + rsub) * DIMC + (c0) + srccol,\
                                dst + ii * 1024);                                   \
                    gload_lds16(Ak + (size_t)(ii * 8 + rsub) * DIMC + (c0) + srccol,\
                                dst + 8192 + ii * 1024);                            \
                }                                                                   \
                _Pragma("unroll")                                                   \
                for (int i = 0; i < 4; ++i) {                                       \
                    int ii = w * 4 + i;                                             \
                    gload_lds16(B + (size_t)(ii * 8 + rsub) * DIMC + (c0) + srccol, \
                                dst + 16384 + ii * 1024);                           \
                }                                                                   \
            }

        STAGE_QK(0, 0);
        int cur = 0;
        for (int c0 = 0; c0 < DIMC; c0 += 64) {
            __syncthreads();
            if (c0 + 64 < DIMC) STAGE_QK(cur ^ 1, c0 + 64);
            const char* sAq = sm + cur * 32768;
            const char* sAk = sAq + 8192;
            const char* sB  = sAq + 16384;
            #pragma unroll
            for (int s = 0; s < 2; ++s) {
                bf16x8 aq[2], ak[2], bfr[4];
                #pragma unroll
                for (int m = 0; m < 2; ++m) {
                    int r = wm * 32 + m * 16 + (lane & 15);
                    int byte = r * 128 + s * 64 + ((lane >> 4) << 4);
                    byte ^= (r & 7) << 4;
                    aq[m] = *(const bf16x8*)(sAq + byte);
                    ak[m] = *(const bf16x8*)(sAk + byte);
                }
                #pragma unroll
                for (int n = 0; n < 4; ++n) {
                    int r = wn * 64 + n * 16 + (lane & 15);
                    int byte = r * 128 + s * 64 + ((lane >> 4) << 4);
                    byte ^= (r & 7) << 4;
                    bfr[n] = *(const bf16x8*)(sB + byte);
                }
                #pragma unroll
                for (int m = 0; m < 2; ++m)
                    #pragma unroll
                    for (int n = 0; n < 4; ++n) {
                        accQ[m][n] = __builtin_amdgcn_mfma_f32_16x16x32_bf16(aq[m], bfr[n], accQ[m][n], 0, 0, 0);
                        accK[m][n] = __builtin_amdgcn_mfma_f32_16x16x32_bf16(ak[m], bfr[n], accK[m][n], 0, 0, 0);
                    }
            }
            cur ^= 1;
        }
        #undef STAGE_QK

        float mv[4];
        #pragma unroll
        for (int n = 0; n < 4; ++n)
            mv[n] = mask[(size_t)b * HW + n0 + wn * 64 + n * 16 + (lane & 15)];
        #pragma unroll
        for (int m = 0; m < 2; ++m)
            #pragma unroll
            for (int n = 0; n < 4; ++n)
                #pragma unroll
                for (int r4 = 0; r4 < 4; ++r4) {
                    accQ[m][n][r4] *= mv[n];
                    accK[m][n][r4] *= mv[n];
                }
        // fused sumsq for q then k
        #pragma unroll
        for (int X = 0; X < 2; ++X)
            #pragma unroll
            for (int m = 0; m < 2; ++m)
                #pragma unroll
                for (int r4 = 0; r4 < 4; ++r4) {
                    float s = 0.f;
                    #pragma unroll
                    for (int n = 0; n < 4; ++n) {
                        float val = X ? accK[m][n][r4] : accQ[m][n][r4];
                        s = fmaf(val, val, s);
                    }
                    s += __shfl_xor(s, 8, 16);
                    s += __shfl_xor(s, 4, 16);
                    s += __shfl_xor(s, 2, 16);
                    s += __shfl_xor(s, 1, 16);
                    if ((lane & 15) == 0) {
                        int j = j0 + wm * 32 + m * 16 + ((lane >> 4) << 2) + r4;
                        atomicAdd(&sumsq[X * 4096 + b * DIMC + j], s);
                    }
                }

        // staged coalesced stores: q then k
        #pragma unroll
        for (int X = 0; X < 2; ++X) {
            unsigned short* outp = X ? k : q;
            __syncthreads();
            #pragma unroll
            for (int m = 0; m < 2; ++m)
                #pragma unroll
                for (int n = 0; n < 4; ++n)
                    #pragma unroll
                    for (int r4 = 0; r4 < 4; ++r4) {
                        int jl = wm * 32 + m * 16 + ((lane >> 4) << 2) + r4;
                        int nl = wn * 64 + n * 16 + (lane & 15);
                        st[jl * 136 + nl] = f2bf(X ? accK[m][n][r4] : accQ[m][n][r4]);
                    }
            __syncthreads();
            #pragma unroll
            for (int it = 0; it < 4; ++it) {
                int idx = t + it * 256, jl = idx >> 4, l16 = idx & 15;
                int4 pv = *(int4*)(sm + jl * 272 + l16 * 16);
                *(int4*)(outp + ((size_t)b * DIMC + j0 + jl) * HW + n0 + l16 * 8) = pv;
            }
        }
    } else {
        // ---------------- v (stored transposed) ----------------
        const unsigned short* Av = Wb + 524288 + (size_t)j0 * DIMC;

        f32x4 acc[2][4];
        #pragma unroll
        for (int m = 0; m < 2; ++m)
            #pragma unroll
            for (int n = 0; n < 4; ++n) acc[m][n] = zero;

        #define STAGE_V(buf, c0)                                                    \
            {                                                                       \
                char* dst = sm + (buf) * 32768;                                     \
                _Pragma("unroll")                                                   \
                for (int i = 0; i < 2; ++i) {                                       \
                    int ii = w * 2 + i;                                             \
                    gload_lds16(Av + (size_t)(ii * 8 + rsub) * DIMC + (c0) + srccol,\
                                dst + ii * 1024);                                   \
                }                                                                   \
                _Pragma("unroll")                                                   \
                for (int i = 0; i < 4; ++i) {                                       \
                    int ii = w * 4 + i;                                             \
                    gload_lds16(B + (size_t)(ii * 8 + rsub) * DIMC + (c0) + srccol, \
                                dst + 16384 + ii * 1024);                           \
                }                                                                   \
            }

        STAGE_V(0, 0);
        int cur = 0;
        for (int c0 = 0; c0 < DIMC; c0 += 64) {
            __syncthreads();
            if (c0 + 64 < DIMC) STAGE_V(cur ^ 1, c0 + 64);
            const char* sA = sm + cur * 32768;
            const char* sB = sA + 16384;
            #pragma unroll
            for (int s = 0; s < 2; ++s) {
                bf16x8 af[2], bfr[4];
                #pragma unroll
                for (int m = 0; m < 2; ++m) {
                    int r = wm * 32 + m * 16 + (lane & 15);
                    int byte = r * 128 + s * 64 + ((lane >> 4) << 4);
                    byte ^= (r & 7) << 4;
                    af[m] = *(const bf16x8*)(sA + byte);
                }
                #pragma unroll
                for (int n = 0; n < 4; ++n) {
                    int r = wn * 64 + n * 16 + (lane & 15);
                    int byte = r * 128 + s * 64 + ((lane >> 4) << 4);
                    byte ^= (r & 7) << 4;
                    bfr[n] = *(const bf16x8*)(sB + byte);
                }
                #pragma unroll
                for (int m = 0; m < 2; ++m)
                    #pragma unroll
                    for (int n = 0; n < 4; ++n)
                        acc[m][n] = __builtin_amdgcn_mfma_f32_16x16x32_bf16(
                            af[m], bfr[n], acc[m][n], 0, 0, 0);
            }
            cur ^= 1;
        }
        #undef STAGE_V

        __syncthreads();
        #pragma unroll
        for (int m = 0; m < 2; ++m)
            #pragma unroll
            for (int n = 0; n < 4; ++n)
                #pragma unroll
                for (int r4 = 0; r4 < 4; ++r4) {
                    int jl = wm * 32 + m * 16 + ((lane >> 4) << 2) + r4;
                    int nl = wn * 64 + n * 16 + (lane & 15);
                    st[nl * 72 + jl] = f2bf(acc[m][n][r4]);
                }
        __syncthreads();
        #pragma unroll
        for (int it = 0; it < 4; ++it) {
            int idx = t + it * 256, nl = idx >> 3, c8 = idx & 7;
            int4 pv = *(int4*)(sm + nl * 144 + c8 * 16);
            *(int4*)(vT + ((size_t)b * HW + n0 + nl) * DIMC + j0 + c8 * 8) = pv;
        }
    }
}

// ---------------------------------------------------------------------------
// K3: MFMA attention logits (NT GEMM). Unchanged.
// ---------------------------------------------------------------------------
__global__ __launch_bounds__(256) void attn_mfma(
    const unsigned short* __restrict__ q, const unsigned short* __restrict__ k,
    float* __restrict__ Spart)
{
    const int bh = blockIdx.x;
    const int chunk = blockIdx.y;
    const unsigned short* Q = q + (size_t)bh * 64 * HW;
    const unsigned short* K = k + (size_t)bh * 64 * HW;

    __shared__ unsigned short sQ[64 * 64];
    __shared__ unsigned short sK[64 * 64];

    const int t = threadIdx.x, lane = t & 63, w = t >> 6;
    const int wm = w >> 1, wn = w & 1;

    f32x4 zero = {0.f, 0.f, 0.f, 0.f};
    f32x4 acc[2][2];
    #pragma unroll
    for (int m = 0; m < 2; ++m)
        #pragma unroll
        for (int n = 0; n < 2; ++n) acc[m][n] = zero;

    int offs[2];
    const unsigned short* gQ[2];
    const unsigned short* gK[2];
    const int nb = chunk * 512;
    #pragma unroll
    for (int i = 0; i < 2; ++i) {
        int ch = t + i * 256, r = ch >> 3, sl = ch & 7;
        offs[i] = r * 128 + ((sl ^ (r & 7)) << 4);
        gQ[i] = Q + (size_t)r * HW + nb + sl * 8;
        gK[i] = K + (size_t)r * HW + nb + sl * 8;
    }

    int4 ra[2], rb[2];
    #pragma unroll
    for (int i = 0; i < 2; ++i) { ra[i] = *(const int4*)(gQ[i]); rb[i] = *(const int4*)(gK[i]); }

    for (int it = 0; it < 8; ++it) {
        __syncthreads();
        #pragma unroll
        for (int i = 0; i < 2; ++i) {
            *(int4*)((char*)sQ + offs[i]) = ra[i];
            *(int4*)((char*)sK + offs[i]) = rb[i];
        }
        __syncthreads();
        if (it < 7) {
            #pragma unroll
            for (int i = 0; i < 2; ++i) {
                ra[i] = *(const int4*)(gQ[i] + (it + 1) * 64);
                rb[i] = *(const int4*)(gK[i] + (it + 1) * 64);
            }
        }
        #pragma unroll
        for (int s = 0; s < 2; ++s) {
            bf16x8 aq[2], bk[2];
            #pragma unroll
            for (int m = 0; m < 2; ++m) {
                int r = wm * 32 + m * 16 + (lane & 15);
                int byte = r * 128 + s * 64 + ((lane >> 4) << 4);
                byte ^= (r & 7) << 4;
                aq[m] = *(const bf16x8*)((const char*)sQ + byte);
            }
            #pragma unroll
            for (int n = 0; n < 2; ++n) {
                int r = wn * 32 + n * 16 + (lane & 15);
                int byte = r * 128 + s * 64 + ((lane >> 4) << 4);
                byte ^= (r & 7) << 4;
                bk[n] = *(const bf16x8*)((const char*)sK + byte);
            }
            #pragma unroll
            for (int m = 0; m < 2; ++m)
                #pragma unroll
                for (int n = 0; n < 2; ++n)
                    acc[m][n] = __builtin_amdgcn_mfma_f32_16x16x32_bf16(
                        aq[m], bk[n], acc[m][n], 0, 0, 0);
        }
    }

    float* Sp = Spart + ((size_t)(bh * 8 + chunk) << 12);
    #pragma unroll
    for (int m = 0; m < 2; ++m)
        #pragma unroll
        for (int n = 0; n < 2; ++n)
            #pragma unroll
            for (int r4 = 0; r4 < 4; ++r4) {
                int r = wm * 32 + m * 16 + ((lane >> 4) << 2) + r4;
                int c = wn * 32 + n * 16 + (lane & 15);
                Sp[r * 64 + c] = acc[m][n][r4];
            }
}

// ---------------------------------------------------------------------------
// K4: combine partials + rsq + scale + row softmax.
// R7: 256 threads (4 lanes per row, shfl width-4 reduces) -- was 64 threads.
// ---------------------------------------------------------------------------
__global__ __launch_bounds__(256) void softmax_attn(
    const float* __restrict__ Spart, const float* __restrict__ sumsq,
    float* __restrict__ attn)
{
    const int bh = blockIdx.x;
    const int b = bh >> 3, h = bh & 7;
    const int t = threadIdx.x;
    const int r = t >> 2;        // 0..63
    const int p = t & 3;         // 16-col part
    __shared__ float srk[64];
    if (t < 64)
        srk[t] = 1.0f / fmaxf(sqrtf(sumsq[4096 + b * DIMC + h * 64 + t]), EPSN);
    __syncthreads();
    const float rq = 1.0f / fmaxf(sqrtf(sumsq[b * DIMC + h * 64 + r]), EPSN);
    const float* Sp = Spart + ((size_t)(bh * 8) << 12) + r * 64 + p * 16;

    float row[16];
    #pragma unroll
    for (int c = 0; c < 16; ++c) {
        float s = 0.f;
        #pragma unroll
        for (int ch = 0; ch < 8; ++ch) s += Sp[(ch << 12) + c];
        row[c] = s * SCALE * rq * srk[p * 16 + c];
    }
    float mx = row[0];
    #pragma unroll
    for (int c = 1; c < 16; ++c) mx = fmaxf(mx, row[c]);
    mx = fmaxf(mx, __shfl_xor(mx, 1, 4));
    mx = fmaxf(mx, __shfl_xor(mx, 2, 4));
    float sum = 0.f;
    #pragma unroll
    for (int c = 0; c < 16; ++c) { row[c] = __expf(row[c] - mx); sum += row[c]; }
    sum += __shfl_xor(sum, 1, 4);
    sum += __shfl_xor(sum, 2, 4);
    const float inv = 1.0f / sum;
    float* A = attn + ((size_t)bh << 12) + r * 64 + p * 16;
    #pragma unroll
    for (int c4 = 0; c4 < 4; ++c4) {
        float4 o = make_float4(row[c4*4+0]*inv, row[c4*4+1]*inv,
                               row[c4*4+2]*inv, row[c4*4+3]*inv);
        *(float4*)(A + c4 * 4) = o;
    }
}

// ---------------------------------------------------------------------------
// K5: fold Wp through attn -> Wp2b bf16 [b][j][c]
// ---------------------------------------------------------------------------
__global__ __launch_bounds__(256) void build_wp2(
    const float* __restrict__ Wp, const float* __restrict__ attn,
    unsigned short* __restrict__ Wp2b)
{
    const int jt = blockIdx.x;
    const int h  = blockIdx.y;
    const int b  = blockIdx.z;

    __shared__ float sA[64][64];
    __shared__ float sW[64][64];

    const int t = threadIdx.x;
    {
        const float* A = attn + ((size_t)(b * 8 + h) << 12);
        for (int i = t * 4; i < 4096; i += 1024)
            *(float4*)&sA[0][i] = *(const float4*)(A + i);
    }
    {
        const int j  = t >> 2;
        const int c0 = (t & 3) * 16;
        #pragma unroll
        for (int i = 0; i < 4; ++i) {
            float4 w4 = *(const float4*)(Wp + (size_t)(jt * 64 + j) * DIMC + h * 64 + c0 + i * 4);
            sW[c0 + i * 4 + 0][j] = w4.x; sW[c0 + i * 4 + 1][j] = w4.y;
            sW[c0 + i * 4 + 2][j] = w4.z; sW[c0 + i * 4 + 3][j] = w4.w;
        }
    }
    __syncthreads();

    const int tx = t & 15, ty = t >> 4;
    float acc[4][4] = {};
    #pragma unroll 16
    for (int c = 0; c < 64; ++c) {
        float wf[4], af[4];
        #pragma unroll
        for (int i = 0; i < 4; ++i) { wf[i] = sW[c][ty * 4 + i]; af[i] = sA[c][tx * 4 + i]; }
        #pragma unroll
        for (int r = 0; r < 4; ++r)
            #pragma unroll
            for (int cc = 0; cc < 4; ++cc)
                acc[r][cc] = fmaf(wf[r], af[cc], acc[r][cc]);
    }

    unsigned short* O = Wp2b + ((size_t)b * DIMC + jt * 64 + ty * 4) * DIMC + h * 64 + tx * 4;
    #pragma unroll
    for (int r = 0; r < 4; ++r) {
        ushort4 o4;
        o4.x = f2bf(acc[r][0]); o4.y = f2bf(acc[r][1]);
        o4.z = f2bf(acc[r][2]); o4.w = f2bf(acc[r][3]);
        *(ushort4*)(O + (size_t)r * DIMC) = o4;
    }
}

// ---------------------------------------------------------------------------
// K6: final MFMA GEMM: out[b][j][n] = sum_c Wp2b[b][j][c] * vT[b][n][c]
// global_load_lds staging; fp32 stores line-granular.
// ---------------------------------------------------------------------------
__global__ __launch_bounds__(256) void final_mfma(
    const unsigned short* __restrict__ Wp2b, const unsigned short* __restrict__ vT,
    float* __restrict__ out)
{
    const int b  = blockIdx.z;
    const int j0 = blockIdx.y * 64;
    const int n0 = blockIdx.x * 128;
    const unsigned short* A = Wp2b + (size_t)b * DIMC * DIMC + (size_t)j0 * DIMC;
    const unsigned short* B = vT + (size_t)b * HW * DIMC + (size_t)n0 * DIMC;

    __shared__ __align__(16) char sm[49152];

    const int t = threadIdx.x, lane = t & 63, w = t >> 6;
    const int wm = w >> 1, wn = w & 1;
    const int rsub = lane >> 3;
    const int srccol = ((lane & 7) ^ rsub) << 3;

    f32x4 zero = {0.f, 0.f, 0.f, 0.f};
    f32x4 acc[2][4];
    #pragma unroll
    for (int m = 0; m < 2; ++m)
        #pragma unroll
        for (int n = 0; n < 4; ++n) acc[m][n] = zero;

    #define STAGE_FIN(buf, c0)                                                  \
        {                                                                       \
            char* dst = sm + (buf) * 24576;                                     \
            _Pragma("unroll")                                                   \
            for (int i = 0; i < 2; ++i) {                                       \
                int ii = w * 2 + i;                                             \
                gload_lds16(A + (size_t)(ii * 8 + rsub) * DIMC + (c0) + srccol, \
                            dst + ii * 1024);                                   \
            }                                                                   \
            _Pragma("unroll")                                                   \
            for (int i = 0; i < 4; ++i) {                                       \
                int ii = w * 4 + i;                                             \
                gload_lds16(B + (size_t)(ii * 8 + rsub) * DIMC + (c0) + srccol, \
                            dst + 8192 + ii * 1024);                            \
            }                                                                   \
        }

    STAGE_FIN(0, 0);
    int cur = 0;
    for (int c0 = 0; c0 < DIMC; c0 += 64) {
        __syncthreads();
        if (c0 + 64 < DIMC) STAGE_FIN(cur ^ 1, c0 + 64);
        const char* sA = sm + cur * 24576;
        const char* sB = sA + 8192;
        #pragma unroll
        for (int s = 0; s < 2; ++s) {
            bf16x8 af[2], bfr[4];
            #pragma unroll
            for (int m = 0; m < 2; ++m) {
                int r = wm * 32 + m * 16 + (lane & 15);
                int byte = r * 128 + s * 64 + ((lane >> 4) << 4);
                byte ^= (r & 7) << 4;
                af[m] = *(const bf16x8*)(sA + byte);
            }
            #pragma unroll
            for (int n = 0; n < 4; ++n) {
                int r = wn * 64 + n * 16 + (lane & 15);
                int byte = r * 128 + s * 64 + ((lane >> 4) << 4);
                byte ^= (r & 7) << 4;
                bfr[n] = *(const bf16x8*)(sB + byte);
            }
            #pragma unroll
            for (int m = 0; m < 2; ++m)
                #pragma unroll
                for (int n = 0; n < 4; ++n)
                    acc[m][n] = __builtin_amdgcn_mfma_f32_16x16x32_bf16(
                        af[m], bfr[n], acc[m][n], 0, 0, 0);
        }
        cur ^= 1;
    }
    #undef STAGE_FIN

    #pragma unroll
    for (int m = 0; m < 2; ++m)
        #pragma unroll
        for (int r4 = 0; r4 < 4; ++r4) {
            int j = j0 + wm * 32 + m * 16 + ((lane >> 4) << 2) + r4;
            size_t rowbase = ((size_t)b * DIMC + j) * HW + n0 + wn * 64 + (lane & 15);
            #pragma unroll
            for (int n = 0; n < 4; ++n)
                out[rowbase + n * 16] = acc[m][n][r4];
        }
}

// ---------------------------------------------------------------------------
// Workspace (bytes):
//   xT    @ 0           33,554,432
//   q     @ 33554432    33,554,432
//   k     @ 67108864    33,554,432
//   vT    @ 100663296   33,554,432
//   Wb    @ 134217728    1,572,864
//   Wp2b  @ 135790592    4,194,304
//   sumsq @ 139984896       32,768   (q rows then k rows, zeroed each call)
//   Spart @ 140017664    8,388,608
//   attn  @ 148406272    1,048,576
// ---------------------------------------------------------------------------
extern "C" void kernel_launch(void* const* d_in, const int* in_sizes, int n_in,
                              void* d_out, int out_size, void* d_ws, size_t ws_size,
                              hipStream_t stream)
{
    const float* x    = (const float*)d_in[0];
    const float* mask = (const float*)d_in[1];
    const float* Wq   = (const float*)d_in[2];
    const float* Wk   = (const float*)d_in[3];
    const float* Wv   = (const float*)d_in[4];
    const float* Wp   = (const float*)d_in[5];
    float* out = (float*)d_out;
    char* wsb = (char*)d_ws;

    unsigned short* xT   = (unsigned short*)(wsb + 0);
    unsigned short* q    = (unsigned short*)(wsb + 33554432);
    unsigned short* k    = (unsigned short*)(wsb + 67108864);
    unsigned short* vT   = (unsigned short*)(wsb + 100663296);
    unsigned short* Wb   = (unsigned short*)(wsb + 134217728);
    unsigned short* Wp2b = (unsigned short*)(wsb + 135790592);
    float* sumsq = (float*)(wsb + 139984896);
    float* Spart = (float*)(wsb + 140017664);
    float* attn  = (float*)(wsb + 148406272);

    hipMemsetAsync(sumsq, 0, 2 * 4096 * sizeof(float), stream);

    convert_w    <<<768,              256, 0, stream>>>(Wq, Wk, Wv, Wb);
    transpose_x  <<<dim3(64, 8, 8),   256, 0, stream>>>(x, xT);
    qkv_mfma     <<<dim3(32, 8, 16),  256, 0, stream>>>(Wb, xT, mask, q, k, vT, sumsq);
    attn_mfma    <<<dim3(64, 8),      256, 0, stream>>>(q, k, Spart);
    softmax_attn <<<64,               256, 0, stream>>>(Spart, sumsq, attn);
    build_wp2    <<<dim3(8, 8, 8),    256, 0, stream>>>(Wp, attn, Wp2b);
    final_mfma   <<<dim3(32, 8, 8),   256, 0, stream>>>(Wp2b, vT, out);
}

// Round 8
// 173.417 us; speedup vs baseline: 3.1201x; 1.0312x over previous
//
#include <hip/hip_runtime.h>
#include <math.h>

#define DIMC 512
#define HW 4096
#define SCALE 0.125f
#define EPSN 1e-12f

typedef __attribute__((ext_vector_type(8))) short bf16x8;
typedef __attribute__((ext_vector_type(4))) float f32x4;

__device__ __forceinline__ unsigned short f2bf(float f) {
    union { float f; unsigned int u; } v; v.f = f;
    unsigned int u = v.u;
    return (unsigned short)((u + 0x7fffu + ((u >> 16) & 1u)) >> 16);
}

union Pack8 { int4 v; unsigned short u[8]; };

// async global->LDS, 16B per lane, wave-uniform LDS base (HW: base + lane*16)
__device__ __forceinline__ void gload_lds16(const unsigned short* src, char* ldst) {
    __builtin_amdgcn_global_load_lds(
        (const __attribute__((address_space(1))) void*)src,
        (__attribute__((address_space(3))) void*)ldst, 16, 0, 0);
}

// ---------------------------------------------------------------------------
// P1: convert Wq,Wk,Wv fp32 -> Wb bf16 [3][512][512] (stacked M=1536)
// ---------------------------------------------------------------------------
__global__ __launch_bounds__(256) void convert_w(
    const float* __restrict__ Wq, const float* __restrict__ Wk,
    const float* __restrict__ Wv, unsigned short* __restrict__ Wb)
{
    int i = (blockIdx.x * 256 + threadIdx.x) * 4;
    int m = i >> 18;
    int off = i & 262143;
    const float* s = (m == 0) ? Wq : (m == 1) ? Wk : Wv;
    float4 v4 = *(const float4*)(s + off);
    ushort4 o;
    o.x = f2bf(v4.x); o.y = f2bf(v4.y); o.z = f2bf(v4.z); o.w = f2bf(v4.w);
    *(ushort4*)(Wb + i) = o;
}

// ---------------------------------------------------------------------------
// P2: transpose+convert x[b][c][n] fp32 -> xT[b][n][c] bf16
// ---------------------------------------------------------------------------
__global__ __launch_bounds__(256) void transpose_x(
    const float* __restrict__ x, unsigned short* __restrict__ xT)
{
    const int b  = blockIdx.z;
    const int c0 = blockIdx.y * 64;
    const int n0 = blockIdx.x * 64;
    __shared__ unsigned short sT[64][65];
    const int t = threadIdx.x;
    #pragma unroll
    for (int i = 0; i < 4; ++i) {
        int ch = t + i * 256;
        int r = ch >> 4, col4 = (ch & 15) * 4;
        float4 v4 = *(const float4*)(x + ((size_t)b * DIMC + c0 + r) * HW + n0 + col4);
        sT[r][col4 + 0] = f2bf(v4.x); sT[r][col4 + 1] = f2bf(v4.y);
        sT[r][col4 + 2] = f2bf(v4.z); sT[r][col4 + 3] = f2bf(v4.w);
    }
    __syncthreads();
    #pragma unroll
    for (int i = 0; i < 2; ++i) {
        int ch = t + i * 256;
        int n = ch >> 3, cc = (ch & 7) * 8;
        Pack8 pk;
        #pragma unroll
        for (int e = 0; e < 8; ++e) pk.u[e] = sT[cc + e][n];
        *(int4*)(xT + ((size_t)b * HW + n0 + n) * DIMC + c0 + cc) = pk.v;
    }
}

// ---------------------------------------------------------------------------
// K1: stacked QKV GEMM, m97-class 128x128 tile (R8).
// M=1536 (Wq|Wk|Wv stacked), N=4096 per batch, K=512. BK=64, dbuf LDS,
// global_load_lds staging with pre-swizzled source. 4 waves (2x2), each owns
// 64x64 (4x4 fragments -> 32 MFMA per K-step).
// which = j0>>9 picks the epilogue: 0/1 = q/k (mask+sumsq+bf16 staged store),
// 2 = v (transposed bf16 staged store).
// ---------------------------------------------------------------------------
__global__ __launch_bounds__(256) void qkv_mfma(
    const unsigned short* __restrict__ Wb, const unsigned short* __restrict__ xT,
    const float* __restrict__ mask,
    unsigned short* __restrict__ q, unsigned short* __restrict__ k,
    unsigned short* __restrict__ vT, float* __restrict__ sumsq)
{
    const int b  = blockIdx.z;
    const int j0 = blockIdx.y * 128;      // 0..1408 (stacked)
    const int n0 = blockIdx.x * 128;
    const int which = j0 >> 9;            // 0=q,1=k,2=v
    const int jloc  = j0 & 511;

    const unsigned short* A = Wb + (size_t)j0 * DIMC;
    const unsigned short* B = xT + (size_t)b * HW * DIMC + (size_t)n0 * DIMC;

    // 2 buffers x (A 16KB + B 16KB); epilogue staging reuses [0..34815]
    __shared__ __align__(16) char sm[65536];

    const int t = threadIdx.x, lane = t & 63, w = t >> 6;
    const int wm = w >> 1, wn = w & 1;
    const int rsub = lane >> 3;                  // row within 8-row group
    const int srccol = ((lane & 7) ^ rsub) << 3; // pre-swizzled src col (elems)

    f32x4 zero = {0.f, 0.f, 0.f, 0.f};
    f32x4 acc[4][4];
    #pragma unroll
    for (int m = 0; m < 4; ++m)
        #pragma unroll
        for (int n = 0; n < 4; ++n) acc[m][n] = zero;

    #define STAGE(buf, c0)                                                      \
        {                                                                       \
            char* dst = sm + (buf) * 32768;                                     \
            _Pragma("unroll")                                                   \
            for (int i = 0; i < 4; ++i) {                                       \
                int ii = w * 4 + i;                                             \
                gload_lds16(A + (size_t)(ii * 8 + rsub) * DIMC + (c0) + srccol, \
                            dst + ii * 1024);                                   \
                gload_lds16(B + (size_t)(ii * 8 + rsub) * DIMC + (c0) + srccol, \
                            dst + 16384 + ii * 1024);                           \
            }                                                                   \
        }

    STAGE(0, 0);
    int cur = 0;
    for (int c0 = 0; c0 < DIMC; c0 += 64) {
        __syncthreads();                    // drains vmcnt: buf[cur] ready
        if (c0 + 64 < DIMC) STAGE(cur ^ 1, c0 + 64);
        const char* sA = sm + cur * 32768;
        const char* sB = sA + 16384;
        #pragma unroll
        for (int s = 0; s < 2; ++s) {
            bf16x8 af[4], bfr[4];
            #pragma unroll
            for (int m = 0; m < 4; ++m) {
                int r = wm * 64 + m * 16 + (lane & 15);
                int byte = r * 128 + s * 64 + ((lane >> 4) << 4);
                byte ^= (r & 7) << 4;
                af[m] = *(const bf16x8*)(sA + byte);
            }
            #pragma unroll
            for (int n = 0; n < 4; ++n) {
                int r = wn * 64 + n * 16 + (lane & 15);
                int byte = r * 128 + s * 64 + ((lane >> 4) << 4);
                byte ^= (r & 7) << 4;
                bfr[n] = *(const bf16x8*)(sB + byte);
            }
            #pragma unroll
            for (int m = 0; m < 4; ++m)
                #pragma unroll
                for (int n = 0; n < 4; ++n)
                    acc[m][n] = __builtin_amdgcn_mfma_f32_16x16x32_bf16(
                        af[m], bfr[n], acc[m][n], 0, 0, 0);
        }
        cur ^= 1;
    }
    #undef STAGE

    unsigned short* st = (unsigned short*)sm;

    if (which < 2) {
        // mask + fused sumsq + staged coalesced store [128j][128n]
        float mv[4];
        #pragma unroll
        for (int n = 0; n < 4; ++n)
            mv[n] = mask[(size_t)b * HW + n0 + wn * 64 + n * 16 + (lane & 15)];
        #pragma unroll
        for (int m = 0; m < 4; ++m)
            #pragma unroll
            for (int n = 0; n < 4; ++n)
                #pragma unroll
                for (int r4 = 0; r4 < 4; ++r4)
                    acc[m][n][r4] *= mv[n];
        #pragma unroll
        for (int m = 0; m < 4; ++m)
            #pragma unroll
            for (int r4 = 0; r4 < 4; ++r4) {
                float s = 0.f;
                #pragma unroll
                for (int n = 0; n < 4; ++n)
                    s = fmaf(acc[m][n][r4], acc[m][n][r4], s);
                s += __shfl_xor(s, 8, 16);
                s += __shfl_xor(s, 4, 16);
                s += __shfl_xor(s, 2, 16);
                s += __shfl_xor(s, 1, 16);
                if ((lane & 15) == 0) {
                    int j = jloc + wm * 64 + m * 16 + ((lane >> 4) << 2) + r4;
                    atomicAdd(&sumsq[which * 4096 + b * DIMC + j], s);
                }
            }

        unsigned short* outp = which ? k : q;
        __syncthreads();
        #pragma unroll
        for (int m = 0; m < 4; ++m)
            #pragma unroll
            for (int n = 0; n < 4; ++n)
                #pragma unroll
                for (int r4 = 0; r4 < 4; ++r4) {
                    int jl = wm * 64 + m * 16 + ((lane >> 4) << 2) + r4;
                    int nl = wn * 64 + n * 16 + (lane & 15);
                    st[jl * 136 + nl] = f2bf(acc[m][n][r4]);
                }
        __syncthreads();
        #pragma unroll
        for (int it = 0; it < 8; ++it) {
            int idx = t + it * 256, jl = idx >> 4, l16 = idx & 15;
            int4 pv = *(int4*)(sm + jl * 272 + l16 * 16);
            *(int4*)(outp + ((size_t)b * DIMC + jloc + jl) * HW + n0 + l16 * 8) = pv;
        }
    } else {
        // v: staged transposed [128n][128j], coalesced along j
        __syncthreads();
        #pragma unroll
        for (int m = 0; m < 4; ++m)
            #pragma unroll
            for (int n = 0; n < 4; ++n)
                #pragma unroll
                for (int r4 = 0; r4 < 4; ++r4) {
                    int jl = wm * 64 + m * 16 + ((lane >> 4) << 2) + r4;
                    int nl = wn * 64 + n * 16 + (lane & 15);
                    st[nl * 136 + jl] = f2bf(acc[m][n][r4]);
                }
        __syncthreads();
        #pragma unroll
        for (int it = 0; it < 8; ++it) {
            int idx = t + it * 256, nl = idx >> 4, c8 = idx & 15;
            int4 pv = *(int4*)(sm + nl * 272 + c8 * 16);
            *(int4*)(vT + ((size_t)b * HW + n0 + nl) * DIMC + jloc + c8 * 8) = pv;
        }
    }
}

// ---------------------------------------------------------------------------
// K3: MFMA attention logits (NT GEMM). Unchanged.
// ---------------------------------------------------------------------------
__global__ __launch_bounds__(256) void attn_mfma(
    const unsigned short* __restrict__ q, const unsigned short* __restrict__ k,
    float* __restrict__ Spart)
{
    const int bh = blockIdx.x;
    const int chunk = blockIdx.y;
    const unsigned short* Q = q + (size_t)bh * 64 * HW;
    const unsigned short* K = k + (size_t)bh * 64 * HW;

    __shared__ unsigned short sQ[64 * 64];
    __shared__ unsigned short sK[64 * 64];

    const int t = threadIdx.x, lane = t & 63, w = t >> 6;
    const int wm = w >> 1, wn = w & 1;

    f32x4 zero = {0.f, 0.f, 0.f, 0.f};
    f32x4 acc[2][2];
    #pragma unroll
    for (int m = 0; m < 2; ++m)
        #pragma unroll
        for (int n = 0; n < 2; ++n) acc[m][n] = zero;

    int offs[2];
    const unsigned short* gQ[2];
    const unsigned short* gK[2];
    const int nb = chunk * 512;
    #pragma unroll
    for (int i = 0; i < 2; ++i) {
        int ch = t + i * 256, r = ch >> 3, sl = ch & 7;
        offs[i] = r * 128 + ((sl ^ (r & 7)) << 4);
        gQ[i] = Q + (size_t)r * HW + nb + sl * 8;
        gK[i] = K + (size_t)r * HW + nb + sl * 8;
    }

    int4 ra[2], rb[2];
    #pragma unroll
    for (int i = 0; i < 2; ++i) { ra[i] = *(const int4*)(gQ[i]); rb[i] = *(const int4*)(gK[i]); }

    for (int it = 0; it < 8; ++it) {
        __syncthreads();
        #pragma unroll
        for (int i = 0; i < 2; ++i) {
            *(int4*)((char*)sQ + offs[i]) = ra[i];
            *(int4*)((char*)sK + offs[i]) = rb[i];
        }
        __syncthreads();
        if (it < 7) {
            #pragma unroll
            for (int i = 0; i < 2; ++i) {
                ra[i] = *(const int4*)(gQ[i] + (it + 1) * 64);
                rb[i] = *(const int4*)(gK[i] + (it + 1) * 64);
            }
        }
        #pragma unroll
        for (int s = 0; s < 2; ++s) {
            bf16x8 aq[2], bk[2];
            #pragma unroll
            for (int m = 0; m < 2; ++m) {
                int r = wm * 32 + m * 16 + (lane & 15);
                int byte = r * 128 + s * 64 + ((lane >> 4) << 4);
                byte ^= (r & 7) << 4;
                aq[m] = *(const bf16x8*)((const char*)sQ + byte);
            }
            #pragma unroll
            for (int n = 0; n < 2; ++n) {
                int r = wn * 32 + n * 16 + (lane & 15);
                int byte = r * 128 + s * 64 + ((lane >> 4) << 4);
                byte ^= (r & 7) << 4;
                bk[n] = *(const bf16x8*)((const char*)sK + byte);
            }
            #pragma unroll
            for (int m = 0; m < 2; ++m)
                #pragma unroll
                for (int n = 0; n < 2; ++n)
                    acc[m][n] = __builtin_amdgcn_mfma_f32_16x16x32_bf16(
                        aq[m], bk[n], acc[m][n], 0, 0, 0);
        }
    }

    float* Sp = Spart + ((size_t)(bh * 8 + chunk) << 12);
    #pragma unroll
    for (int m = 0; m < 2; ++m)
        #pragma unroll
        for (int n = 0; n < 2; ++n)
            #pragma unroll
            for (int r4 = 0; r4 < 4; ++r4) {
                int r = wm * 32 + m * 16 + ((lane >> 4) << 2) + r4;
                int c = wn * 32 + n * 16 + (lane & 15);
                Sp[r * 64 + c] = acc[m][n][r4];
            }
}

// ---------------------------------------------------------------------------
// K4: combine partials + rsq + scale + row softmax. 256 threads, 4 lanes/row.
// ---------------------------------------------------------------------------
__global__ __launch_bounds__(256) void softmax_attn(
    const float* __restrict__ Spart, const float* __restrict__ sumsq,
    float* __restrict__ attn)
{
    const int bh = blockIdx.x;
    const int b = bh >> 3, h = bh & 7;
    const int t = threadIdx.x;
    const int r = t >> 2;
    const int p = t & 3;
    __shared__ float srk[64];
    if (t < 64)
        srk[t] = 1.0f / fmaxf(sqrtf(sumsq[4096 + b * DIMC + h * 64 + t]), EPSN);
    __syncthreads();
    const float rq = 1.0f / fmaxf(sqrtf(sumsq[b * DIMC + h * 64 + r]), EPSN);
    const float* Sp = Spart + ((size_t)(bh * 8) << 12) + r * 64 + p * 16;

    float row[16];
    #pragma unroll
    for (int c = 0; c < 16; ++c) {
        float s = 0.f;
        #pragma unroll
        for (int ch = 0; ch < 8; ++ch) s += Sp[(ch << 12) + c];
        row[c] = s * SCALE * rq * srk[p * 16 + c];
    }
    float mx = row[0];
    #pragma unroll
    for (int c = 1; c < 16; ++c) mx = fmaxf(mx, row[c]);
    mx = fmaxf(mx, __shfl_xor(mx, 1, 4));
    mx = fmaxf(mx, __shfl_xor(mx, 2, 4));
    float sum = 0.f;
    #pragma unroll
    for (int c = 0; c < 16; ++c) { row[c] = __expf(row[c] - mx); sum += row[c]; }
    sum += __shfl_xor(sum, 1, 4);
    sum += __shfl_xor(sum, 2, 4);
    const float inv = 1.0f / sum;
    float* A = attn + ((size_t)bh << 12) + r * 64 + p * 16;
    #pragma unroll
    for (int c4 = 0; c4 < 4; ++c4) {
        float4 o = make_float4(row[c4*4+0]*inv, row[c4*4+1]*inv,
                               row[c4*4+2]*inv, row[c4*4+3]*inv);
        *(float4*)(A + c4 * 4) = o;
    }
}

// ---------------------------------------------------------------------------
// K5: fold Wp through attn -> Wp2b bf16 [b][j][c]
// ---------------------------------------------------------------------------
__global__ __launch_bounds__(256) void build_wp2(
    const float* __restrict__ Wp, const float* __restrict__ attn,
    unsigned short* __restrict__ Wp2b)
{
    const int jt = blockIdx.x;
    const int h  = blockIdx.y;
    const int b  = blockIdx.z;

    __shared__ float sA[64][64];
    __shared__ float sW[64][64];

    const int t = threadIdx.x;
    {
        const float* A = attn + ((size_t)(b * 8 + h) << 12);
        for (int i = t * 4; i < 4096; i += 1024)
            *(float4*)&sA[0][i] = *(const float4*)(A + i);
    }
    {
        const int j  = t >> 2;
        const int c0 = (t & 3) * 16;
        #pragma unroll
        for (int i = 0; i < 4; ++i) {
            float4 w4 = *(const float4*)(Wp + (size_t)(jt * 64 + j) * DIMC + h * 64 + c0 + i * 4);
            sW[c0 + i * 4 + 0][j] = w4.x; sW[c0 + i * 4 + 1][j] = w4.y;
            sW[c0 + i * 4 + 2][j] = w4.z; sW[c0 + i * 4 + 3][j] = w4.w;
        }
    }
    __syncthreads();

    const int tx = t & 15, ty = t >> 4;
    float acc[4][4] = {};
    #pragma unroll 16
    for (int c = 0; c < 64; ++c) {
        float wf[4], af[4];
        #pragma unroll
        for (int i = 0; i < 4; ++i) { wf[i] = sW[c][ty * 4 + i]; af[i] = sA[c][tx * 4 + i]; }
        #pragma unroll
        for (int r = 0; r < 4; ++r)
            #pragma unroll
            for (int cc = 0; cc < 4; ++cc)
                acc[r][cc] = fmaf(wf[r], af[cc], acc[r][cc]);
    }

    unsigned short* O = Wp2b + ((size_t)b * DIMC + jt * 64 + ty * 4) * DIMC + h * 64 + tx * 4;
    #pragma unroll
    for (int r = 0; r < 4; ++r) {
        ushort4 o4;
        o4.x = f2bf(acc[r][0]); o4.y = f2bf(acc[r][1]);
        o4.z = f2bf(acc[r][2]); o4.w = f2bf(acc[r][3]);
        *(ushort4*)(O + (size_t)r * DIMC) = o4;
    }
}

// ---------------------------------------------------------------------------
// K6: final MFMA GEMM (128x128 tile, same structure as qkv):
//   out[b][j][n] = sum_c Wp2b[b][j][c] * vT[b][n][c]; fp32 direct stores.
// ---------------------------------------------------------------------------
__global__ __launch_bounds__(256) void final_mfma(
    const unsigned short* __restrict__ Wp2b, const unsigned short* __restrict__ vT,
    float* __restrict__ out)
{
    const int b  = blockIdx.z;
    const int j0 = blockIdx.y * 128;
    const int n0 = blockIdx.x * 128;
    const unsigned short* A = Wp2b + (size_t)b * DIMC * DIMC + (size_t)j0 * DIMC;
    const unsigned short* B = vT + (size_t)b * HW * DIMC + (size_t)n0 * DIMC;

    __shared__ __align__(16) char sm[65536];

    const int t = threadIdx.x, lane = t & 63, w = t >> 6;
    const int wm = w >> 1, wn = w & 1;
    const int rsub = lane >> 3;
    const int srccol = ((lane & 7) ^ rsub) << 3;

    f32x4 zero = {0.f, 0.f, 0.f, 0.f};
    f32x4 acc[4][4];
    #pragma unroll
    for (int m = 0; m < 4; ++m)
        #pragma unroll
        for (int n = 0; n < 4; ++n) acc[m][n] = zero;

    #define STAGE_FIN(buf, c0)                                                  \
        {                                                                       \
            char* dst = sm + (buf) * 32768;                                     \
            _Pragma("unroll")                                                   \
            for (int i = 0; i < 4; ++i) {                                       \
                int ii = w * 4 + i;                                             \
                gload_lds16(A + (size_t)(ii * 8 + rsub) * DIMC + (c0) + srccol, \
                            dst + ii * 1024);                                   \
                gload_lds16(B + (size_t)(ii * 8 + rsub) * DIMC + (c0) + srccol, \
                            dst + 16384 + ii * 1024);                           \
            }                                                                   \
        }

    STAGE_FIN(0, 0);
    int cur = 0;
    for (int c0 = 0; c0 < DIMC; c0 += 64) {
        __syncthreads();
        if (c0 + 64 < DIMC) STAGE_FIN(cur ^ 1, c0 + 64);
        const char* sA = sm + cur * 32768;
        const char* sB = sA + 16384;
        #pragma unroll
        for (int s = 0; s < 2; ++s) {
            bf16x8 af[4], bfr[4];
            #pragma unroll
            for (int m = 0; m < 4; ++m) {
                int r = wm * 64 + m * 16 + (lane & 15);
                int byte = r * 128 + s * 64 + ((lane >> 4) << 4);
                byte ^= (r & 7) << 4;
                af[m] = *(const bf16x8*)(sA + byte);
            }
            #pragma unroll
            for (int n = 0; n < 4; ++n) {
                int r = wn * 64 + n * 16 + (lane & 15);
                int byte = r * 128 + s * 64 + ((lane >> 4) << 4);
                byte ^= (r & 7) << 4;
                bfr[n] = *(const bf16x8*)(sB + byte);
            }
            #pragma unroll
            for (int m = 0; m < 4; ++m)
                #pragma unroll
                for (int n = 0; n < 4; ++n)
                    acc[m][n] = __builtin_amdgcn_mfma_f32_16x16x32_bf16(
                        af[m], bfr[n], acc[m][n], 0, 0, 0);
        }
        cur ^= 1;
    }
    #undef STAGE_FIN

    #pragma unroll
    for (int m = 0; m < 4; ++m)
        #pragma unroll
        for (int r4 = 0; r4 < 4; ++r4) {
            int j = j0 + wm * 64 + m * 16 + ((lane >> 4) << 2) + r4;
            size_t rowbase = ((size_t)b * DIMC + j) * HW + n0 + wn * 64 + (lane & 15);
            #pragma unroll
            for (int n = 0; n < 4; ++n)
                out[rowbase + n * 16] = acc[m][n][r4];
        }
}

// ---------------------------------------------------------------------------
// Workspace (bytes):
//   xT    @ 0           33,554,432
//   q     @ 33554432    33,554,432
//   k     @ 67108864    33,554,432
//   vT    @ 100663296   33,554,432
//   Wb    @ 134217728    1,572,864
//   Wp2b  @ 135790592    4,194,304
//   sumsq @ 139984896       32,768   (q rows then k rows, zeroed each call)
//   Spart @ 140017664    8,388,608
//   attn  @ 148406272    1,048,576
// ---------------------------------------------------------------------------
extern "C" void kernel_launch(void* const* d_in, const int* in_sizes, int n_in,
                              void* d_out, int out_size, void* d_ws, size_t ws_size,
                              hipStream_t stream)
{
    const float* x    = (const float*)d_in[0];
    const float* mask = (const float*)d_in[1];
    const float* Wq   = (const float*)d_in[2];
    const float* Wk   = (const float*)d_in[3];
    const float* Wv   = (const float*)d_in[4];
    const float* Wp   = (const float*)d_in[5];
    float* out = (float*)d_out;
    char* wsb = (char*)d_ws;

    unsigned short* xT   = (unsigned short*)(wsb + 0);
    unsigned short* q    = (unsigned short*)(wsb + 33554432);
    unsigned short* k    = (unsigned short*)(wsb + 67108864);
    unsigned short* vT   = (unsigned short*)(wsb + 100663296);
    unsigned short* Wb   = (unsigned short*)(wsb + 134217728);
    unsigned short* Wp2b = (unsigned short*)(wsb + 135790592);
    float* sumsq = (float*)(wsb + 139984896);
    float* Spart = (float*)(wsb + 140017664);
    float* attn  = (float*)(wsb + 148406272);

    hipMemsetAsync(sumsq, 0, 2 * 4096 * sizeof(float), stream);

    convert_w    <<<768,              256, 0, stream>>>(Wq, Wk, Wv, Wb);
    transpose_x  <<<dim3(64, 8, 8),   256, 0, stream>>>(x, xT);
    qkv_mfma     <<<dim3(32, 12, 8),  256, 0, stream>>>(Wb, xT, mask, q, k, vT, sumsq);
    attn_mfma    <<<dim3(64, 8),      256, 0, stream>>>(q, k, Spart);
    softmax_attn <<<64,               256, 0, stream>>>(Spart, sumsq, attn);
    build_wp2    <<<dim3(8, 8, 8),    256, 0, stream>>>(Wp, attn, Wp2b);
    final_mfma   <<<dim3(32, 4, 8),   256, 0, stream>>>(Wp2b, vT, out);
}

// Round 9
// 132.351 us; speedup vs baseline: 4.0882x; 1.3103x over previous
//
#include <hip/hip_runtime.h>
#include <math.h>

#define DIMC 512
#define HW 4096
#define SCALE 0.125f
#define EPSN 1e-12f

typedef __attribute__((ext_vector_type(8))) short bf16x8;
typedef __attribute__((ext_vector_type(4))) float f32x4;

__device__ __forceinline__ unsigned short f2bf(float f) {
    union { float f; unsigned int u; } v; v.f = f;
    unsigned int u = v.u;
    return (unsigned short)((u + 0x7fffu + ((u >> 16) & 1u)) >> 16);
}
__device__ __forceinline__ float bf2f(unsigned short h) {
    union { unsigned int u; float f; } v; v.u = ((unsigned int)h) << 16;
    return v.f;
}

union Pack8 { int4 v; unsigned short u[8]; };

// async global->LDS, 16B per lane, wave-uniform LDS base (HW: base + lane*16)
__device__ __forceinline__ void gload_lds16(const unsigned short* src, char* ldst) {
    __builtin_amdgcn_global_load_lds(
        (const __attribute__((address_space(1))) void*)src,
        (__attribute__((address_space(3))) void*)ldst, 16, 0, 0);
}

// ---------------------------------------------------------------------------
// P1: convert Wq,Wk fp32 -> Wb bf16 [2][512][512] (stacked)
// ---------------------------------------------------------------------------
__global__ __launch_bounds__(256) void convert_w(
    const float* __restrict__ Wq, const float* __restrict__ Wk,
    unsigned short* __restrict__ Wb)
{
    int i = (blockIdx.x * 256 + threadIdx.x) * 4;   // [0, 524288)
    const float* s = (i < 262144) ? Wq : Wk;
    int off = i & 262143;
    float4 v4 = *(const float4*)(s + off);
    ushort4 o;
    o.x = f2bf(v4.x); o.y = f2bf(v4.y); o.z = f2bf(v4.z); o.w = f2bf(v4.w);
    *(ushort4*)(Wb + i) = o;
}

// ---------------------------------------------------------------------------
// P1b: WvT[c3][c'] = bf16(Wv[c'][c3])  (512x512 transpose+convert)
// ---------------------------------------------------------------------------
__global__ __launch_bounds__(256) void wvt_conv(
    const float* __restrict__ Wv, unsigned short* __restrict__ WvT)
{
    const int cp0 = blockIdx.y * 64;   // c' tile
    const int c30 = blockIdx.x * 64;   // c3 tile
    __shared__ unsigned short sT[64][65];
    const int t = threadIdx.x;
    #pragma unroll
    for (int i = 0; i < 4; ++i) {
        int ch = t + i * 256;
        int r = ch >> 4, col4 = (ch & 15) * 4;
        float4 v4 = *(const float4*)(Wv + (size_t)(cp0 + r) * DIMC + c30 + col4);
        sT[r][col4 + 0] = f2bf(v4.x); sT[r][col4 + 1] = f2bf(v4.y);
        sT[r][col4 + 2] = f2bf(v4.z); sT[r][col4 + 3] = f2bf(v4.w);
    }
    __syncthreads();
    #pragma unroll
    for (int i = 0; i < 2; ++i) {
        int ch = t + i * 256;
        int n = ch >> 3, cc = (ch & 7) * 8;   // n = c3-local
        Pack8 pk;
        #pragma unroll
        for (int e = 0; e < 8; ++e) pk.u[e] = sT[cc + e][n];
        *(int4*)(WvT + (size_t)(c30 + n) * DIMC + cp0 + cc) = pk.v;
    }
}

// ---------------------------------------------------------------------------
// P2: prep_x: x[b][c][n] fp32 -> xT[b][n][c] bf16 (unmasked, for final GEMM B)
//                            -> xmb[b][c][n] bf16 masked (for Gram)
// ---------------------------------------------------------------------------
__global__ __launch_bounds__(256) void prep_x(
    const float* __restrict__ x, const float* __restrict__ mask,
    unsigned short* __restrict__ xT, unsigned short* __restrict__ xmb)
{
    const int b  = blockIdx.z;
    const int c0 = blockIdx.y * 64;
    const int n0 = blockIdx.x * 64;
    __shared__ unsigned short sT[64][65];
    const int t = threadIdx.x;
    #pragma unroll
    for (int i = 0; i < 4; ++i) {
        int ch = t + i * 256;
        int r = ch >> 4, col4 = (ch & 15) * 4;
        float4 v4 = *(const float4*)(x + ((size_t)b * DIMC + c0 + r) * HW + n0 + col4);
        sT[r][col4 + 0] = f2bf(v4.x); sT[r][col4 + 1] = f2bf(v4.y);
        sT[r][col4 + 2] = f2bf(v4.z); sT[r][col4 + 3] = f2bf(v4.w);
        float4 mv = *(const float4*)(mask + (size_t)b * HW + n0 + col4);
        ushort4 xm;
        xm.x = f2bf(v4.x * mv.x); xm.y = f2bf(v4.y * mv.y);
        xm.z = f2bf(v4.z * mv.z); xm.w = f2bf(v4.w * mv.w);
        *(ushort4*)(xmb + ((size_t)b * DIMC + c0 + r) * HW + n0 + col4) = xm;
    }
    __syncthreads();
    #pragma unroll
    for (int i = 0; i < 2; ++i) {
        int ch = t + i * 256;
        int n = ch >> 3, cc = (ch & 7) * 8;
        Pack8 pk;
        #pragma unroll
        for (int e = 0; e < 8; ++e) pk.u[e] = sT[cc + e][n];
        *(int4*)(xT + ((size_t)b * HW + n0 + n) * DIMC + c0 + cc) = pk.v;
    }
}

// ---------------------------------------------------------------------------
// K1: Gram GEMM: G[b][cA][cB] = sum_n xmb[cA][n] * xmb[cB][n]  (NT, K=4096)
// 64(cA) x 128(cB) tile, BK=64, dbuf gload_lds (R6-proven structure).
// ---------------------------------------------------------------------------
__global__ __launch_bounds__(256) void gram_mfma(
    const unsigned short* __restrict__ xmb, unsigned short* __restrict__ G)
{
    const int b   = blockIdx.z;
    const int cA0 = blockIdx.y * 64;
    const int cB0 = blockIdx.x * 128;
    const unsigned short* A = xmb + (size_t)b * DIMC * HW + (size_t)cA0 * HW;
    const unsigned short* B = xmb + (size_t)b * DIMC * HW + (size_t)cB0 * HW;

    __shared__ __align__(16) char sm[49152];   // 2 x (A 8KB + B 16KB)

    const int t = threadIdx.x, lane = t & 63, w = t >> 6;
    const int wm = w >> 1, wn = w & 1;
    const int rsub = lane >> 3;
    const int srccol = ((lane & 7) ^ rsub) << 3;

    f32x4 zero = {0.f, 0.f, 0.f, 0.f};
    f32x4 acc[2][4];
    #pragma unroll
    for (int m = 0; m < 2; ++m)
        #pragma unroll
        for (int n = 0; n < 4; ++n) acc[m][n] = zero;

    #define STAGE_G(buf, c0)                                                  \
        {                                                                     \
            char* dst = sm + (buf) * 24576;                                   \
            _Pragma("unroll")                                                 \
            for (int i = 0; i < 2; ++i) {                                     \
                int ii = w * 2 + i;                                           \
                gload_lds16(A + (size_t)(ii * 8 + rsub) * HW + (c0) + srccol, \
                            dst + ii * 1024);                                 \
            }                                                                 \
            _Pragma("unroll")                                                 \
            for (int i = 0; i < 4; ++i) {                                     \
                int ii = w * 4 + i;                                           \
                gload_lds16(B + (size_t)(ii * 8 + rsub) * HW + (c0) + srccol, \
                            dst + 8192 + ii * 1024);                          \
            }                                                                 \
        }

    STAGE_G(0, 0);
    int cur = 0;
    for (int c0 = 0; c0 < HW; c0 += 64) {
        __syncthreads();
        if (c0 + 64 < HW) STAGE_G(cur ^ 1, c0 + 64);
        const char* sA = sm + cur * 24576;
        const char* sB = sA + 8192;
        #pragma unroll
        for (int s = 0; s < 2; ++s) {
            bf16x8 af[2], bfr[4];
            #pragma unroll
            for (int m = 0; m < 2; ++m) {
                int r = wm * 32 + m * 16 + (lane & 15);
                int byte = r * 128 + s * 64 + ((lane >> 4) << 4);
                byte ^= (r & 7) << 4;
                af[m] = *(const bf16x8*)(sA + byte);
            }
            #pragma unroll
            for (int n = 0; n < 4; ++n) {
                int r = wn * 64 + n * 16 + (lane & 15);
                int byte = r * 128 + s * 64 + ((lane >> 4) << 4);
                byte ^= (r & 7) << 4;
                bfr[n] = *(const bf16x8*)(sB + byte);
            }
            #pragma unroll
            for (int m = 0; m < 2; ++m)
                #pragma unroll
                for (int n = 0; n < 4; ++n)
                    acc[m][n] = __builtin_amdgcn_mfma_f32_16x16x32_bf16(
                        af[m], bfr[n], acc[m][n], 0, 0, 0);
        }
        cur ^= 1;
    }
    #undef STAGE_G

    // staged coalesced bf16 store [64][128] -> G[b][cA][cB], row stride 512
    unsigned short* st = (unsigned short*)sm;
    __syncthreads();
    #pragma unroll
    for (int m = 0; m < 2; ++m)
        #pragma unroll
        for (int n = 0; n < 4; ++n)
            #pragma unroll
            for (int r4 = 0; r4 < 4; ++r4) {
                int jl = wm * 32 + m * 16 + ((lane >> 4) << 2) + r4;
                int nl = wn * 64 + n * 16 + (lane & 15);
                st[jl * 136 + nl] = f2bf(acc[m][n][r4]);
            }
    __syncthreads();
    #pragma unroll
    for (int it = 0; it < 4; ++it) {
        int idx = t + it * 256, jl = idx >> 4, l16 = idx & 15;
        int4 pv = *(int4*)((char*)sm + jl * 272 + l16 * 16);
        *(int4*)(G + ((size_t)b * DIMC + cA0 + jl) * DIMC + cB0 + l16 * 8) = pv;
    }
}

// ---------------------------------------------------------------------------
// K2: generic 128x128 NT GEMM, K=512, all row strides 512, bf16 out.
// C[b][j][n] = sum_k A[b][j][k] * B[b][n][k]   (batch strides as args)
// Used for: TU = [Wq|Wk] * G  (B = G rows, valid by G symmetry)
//           Wf = Wp2b * Wv    (B = WvT rows)
// ---------------------------------------------------------------------------
__global__ __launch_bounds__(256) void gemm_nn_128(
    const unsigned short* __restrict__ Ag, size_t aBatch,
    const unsigned short* __restrict__ Bg, size_t bBatch,
    unsigned short* __restrict__ Cg, size_t cBatch)
{
    const int b  = blockIdx.z;
    const int j0 = blockIdx.y * 128;
    const int n0 = blockIdx.x * 128;
    const unsigned short* A = Ag + (size_t)b * aBatch + (size_t)j0 * DIMC;
    const unsigned short* B = Bg + (size_t)b * bBatch + (size_t)n0 * DIMC;

    __shared__ __align__(16) char sm[65536];

    const int t = threadIdx.x, lane = t & 63, w = t >> 6;
    const int wm = w >> 1, wn = w & 1;
    const int rsub = lane >> 3;
    const int srccol = ((lane & 7) ^ rsub) << 3;

    f32x4 zero = {0.f, 0.f, 0.f, 0.f};
    f32x4 acc[4][4];
    #pragma unroll
    for (int m = 0; m < 4; ++m)
        #pragma unroll
        for (int n = 0; n < 4; ++n) acc[m][n] = zero;

    #define STAGE_NN(buf, c0)                                                   \
        {                                                                       \
            char* dst = sm + (buf) * 32768;                                     \
            _Pragma("unroll")                                                   \
            for (int i = 0; i < 4; ++i) {                                       \
                int ii = w * 4 + i;                                             \
                gload_lds16(A + (size_t)(ii * 8 + rsub) * DIMC + (c0) + srccol, \
                            dst + ii * 1024);                                   \
                gload_lds16(B + (size_t)(ii * 8 + rsub) * DIMC + (c0) + srccol, \
                            dst + 16384 + ii * 1024);                           \
            }                                                                   \
        }

    STAGE_NN(0, 0);
    int cur = 0;
    for (int c0 = 0; c0 < DIMC; c0 += 64) {
        __syncthreads();
        if (c0 + 64 < DIMC) STAGE_NN(cur ^ 1, c0 + 64);
        const char* sA = sm + cur * 32768;
        const char* sB = sA + 16384;
        #pragma unroll
        for (int s = 0; s < 2; ++s) {
            bf16x8 af[4], bfr[4];
            #pragma unroll
            for (int m = 0; m < 4; ++m) {
                int r = wm * 64 + m * 16 + (lane & 15);
                int byte = r * 128 + s * 64 + ((lane >> 4) << 4);
                byte ^= (r & 7) << 4;
                af[m] = *(const bf16x8*)(sA + byte);
            }
            #pragma unroll
            for (int n = 0; n < 4; ++n) {
                int r = wn * 64 + n * 16 + (lane & 15);
                int byte = r * 128 + s * 64 + ((lane >> 4) << 4);
                byte ^= (r & 7) << 4;
                bfr[n] = *(const bf16x8*)(sB + byte);
            }
            #pragma unroll
            for (int m = 0; m < 4; ++m)
                #pragma unroll
                for (int n = 0; n < 4; ++n)
                    acc[m][n] = __builtin_amdgcn_mfma_f32_16x16x32_bf16(
                        af[m], bfr[n], acc[m][n], 0, 0, 0);
        }
        cur ^= 1;
    }
    #undef STAGE_NN

    unsigned short* st = (unsigned short*)sm;
    __syncthreads();
    #pragma unroll
    for (int m = 0; m < 4; ++m)
        #pragma unroll
        for (int n = 0; n < 4; ++n)
            #pragma unroll
            for (int r4 = 0; r4 < 4; ++r4) {
                int jl = wm * 64 + m * 16 + ((lane >> 4) << 2) + r4;
                int nl = wn * 64 + n * 16 + (lane & 15);
                st[jl * 136 + nl] = f2bf(acc[m][n][r4]);
            }
    __syncthreads();
    #pragma unroll
    for (int it = 0; it < 8; ++it) {
        int idx = t + it * 256, jl = idx >> 4, l16 = idx & 15;
        int4 pv = *(int4*)((char*)sm + jl * 272 + l16 * 16);
        *(int4*)(Cg + (size_t)b * cBatch + (size_t)(j0 + jl) * DIMC + n0 + l16 * 8) = pv;
    }
}

// ---------------------------------------------------------------------------
// K3: sumsq via row-dots: sumsq_q[b][j] = dot(T[b][j], Wq[j]);
//     sumsq_k[b][j] = dot(U[b][j], Wk[j]).  TU stacked j in [0,1024).
// ---------------------------------------------------------------------------
__global__ __launch_bounds__(256) void sumsq_dot(
    const unsigned short* __restrict__ TU, const unsigned short* __restrict__ Wb,
    float* __restrict__ sumsq)
{
    const int row  = blockIdx.x * 4 + (threadIdx.x >> 6);   // 0..8191
    const int lane = threadIdx.x & 63;
    const int b = row >> 10, jj = row & 1023;
    Pack8 a, wv;
    a.v  = *(const int4*)(TU + ((size_t)b * 1024 + jj) * DIMC + lane * 8);
    wv.v = *(const int4*)(Wb + (size_t)jj * DIMC + lane * 8);
    float s = 0.f;
    #pragma unroll
    for (int e = 0; e < 8; ++e) s = fmaf(bf2f(a.u[e]), bf2f(wv.u[e]), s);
    #pragma unroll
    for (int o = 32; o > 0; o >>= 1) s += __shfl_down(s, o, 64);
    if (lane == 0)
        sumsq[(jj >> 9) * 4096 + b * DIMC + (jj & 511)] = s;
}

// ---------------------------------------------------------------------------
// K4: fused S + softmax per (b,h):
//   S[r][c] = sum_k T[h*64+r][k] * Wk[h*64+c][k]   (64x64, K=512)
//   attn = softmax_c(S * SCALE * rsq_q[r] * rsq_k[c])
// ---------------------------------------------------------------------------
__global__ __launch_bounds__(256) void s_softmax(
    const unsigned short* __restrict__ TU, const unsigned short* __restrict__ Wb,
    const float* __restrict__ sumsq, float* __restrict__ attn)
{
    const int bh = blockIdx.x;
    const int b = bh >> 3, h = bh & 7;
    const unsigned short* A = TU + ((size_t)b * 1024 + h * 64) * DIMC;   // T rows
    const unsigned short* B = Wb + 262144 + (size_t)(h * 64) * DIMC;     // Wk rows

    __shared__ __align__(16) char sm[32768];   // 2 x (A 8KB + B 8KB)
    __shared__ float sS[64][65];
    __shared__ float srk[64];

    const int t = threadIdx.x, lane = t & 63, w = t >> 6;
    const int wm = w >> 1, wn = w & 1;
    const int rsub = lane >> 3;
    const int srccol = ((lane & 7) ^ rsub) << 3;

    f32x4 zero = {0.f, 0.f, 0.f, 0.f};
    f32x4 acc[2][2];
    #pragma unroll
    for (int m = 0; m < 2; ++m)
        #pragma unroll
        for (int n = 0; n < 2; ++n) acc[m][n] = zero;

    #define STAGE_S(buf, c0)                                                    \
        {                                                                       \
            char* dst = sm + (buf) * 16384;                                     \
            _Pragma("unroll")                                                   \
            for (int i = 0; i < 2; ++i) {                                       \
                int ii = w * 2 + i;                                             \
                gload_lds16(A + (size_t)(ii * 8 + rsub) * DIMC + (c0) + srccol, \
                            dst + ii * 1024);                                   \
                gload_lds16(B + (size_t)(ii * 8 + rsub) * DIMC + (c0) + srccol, \
                            dst + 8192 + ii * 1024);                            \
            }                                                                   \
        }

    STAGE_S(0, 0);
    int cur = 0;
    for (int c0 = 0; c0 < DIMC; c0 += 64) {
        __syncthreads();
        if (c0 + 64 < DIMC) STAGE_S(cur ^ 1, c0 + 64);
        const char* sA = sm + cur * 16384;
        const char* sB = sA + 8192;
        #pragma unroll
        for (int s = 0; s < 2; ++s) {
            bf16x8 aq[2], bk[2];
            #pragma unroll
            for (int m = 0; m < 2; ++m) {
                int r = wm * 32 + m * 16 + (lane & 15);
                int byte = r * 128 + s * 64 + ((lane >> 4) << 4);
                byte ^= (r & 7) << 4;
                aq[m] = *(const bf16x8*)(sA + byte);
            }
            #pragma unroll
            for (int n = 0; n < 2; ++n) {
                int r = wn * 32 + n * 16 + (lane & 15);
                int byte = r * 128 + s * 64 + ((lane >> 4) << 4);
                byte ^= (r & 7) << 4;
                bk[n] = *(const bf16x8*)(sB + byte);
            }
            #pragma unroll
            for (int m = 0; m < 2; ++m)
                #pragma unroll
                for (int n = 0; n < 2; ++n)
                    acc[m][n] = __builtin_amdgcn_mfma_f32_16x16x32_bf16(
                        aq[m], bk[n], acc[m][n], 0, 0, 0);
        }
        cur ^= 1;
    }
    #undef STAGE_S

    // stage S to LDS + rsq_k table, then softmax
    #pragma unroll
    for (int m = 0; m < 2; ++m)
        #pragma unroll
        for (int n = 0; n < 2; ++n)
            #pragma unroll
            for (int r4 = 0; r4 < 4; ++r4) {
                int r = wm * 32 + m * 16 + ((lane >> 4) << 2) + r4;
                int c = wn * 32 + n * 16 + (lane & 15);
                sS[r][c] = acc[m][n][r4];
            }
    if (t < 64)
        srk[t] = 1.0f / fmaxf(sqrtf(sumsq[4096 + b * DIMC + h * 64 + t]), EPSN);
    __syncthreads();

    const int r = t >> 2;       // 0..63
    const int p = t & 3;        // 16-col part
    const float rq = 1.0f / fmaxf(sqrtf(sumsq[b * DIMC + h * 64 + r]), EPSN);
    float row[16];
    #pragma unroll
    for (int c = 0; c < 16; ++c)
        row[c] = sS[r][p * 16 + c] * SCALE * rq * srk[p * 16 + c];
    float mx = row[0];
    #pragma unroll
    for (int c = 1; c < 16; ++c) mx = fmaxf(mx, row[c]);
    mx = fmaxf(mx, __shfl_xor(mx, 1, 4));
    mx = fmaxf(mx, __shfl_xor(mx, 2, 4));
    float sum = 0.f;
    #pragma unroll
    for (int c = 0; c < 16; ++c) { row[c] = __expf(row[c] - mx); sum += row[c]; }
    sum += __shfl_xor(sum, 1, 4);
    sum += __shfl_xor(sum, 2, 4);
    const float inv = 1.0f / sum;
    float* Ao = attn + ((size_t)bh << 12) + r * 64 + p * 16;
    #pragma unroll
    for (int c4 = 0; c4 < 4; ++c4) {
        float4 o = make_float4(row[c4*4+0]*inv, row[c4*4+1]*inv,
                               row[c4*4+2]*inv, row[c4*4+3]*inv);
        *(float4*)(Ao + c4 * 4) = o;
    }
}

// ---------------------------------------------------------------------------
// K5: fold Wp through attn -> Wp2b bf16 [b][j][c]   (unchanged)
// ---------------------------------------------------------------------------
__global__ __launch_bounds__(256) void build_wp2(
    const float* __restrict__ Wp, const float* __restrict__ attn,
    unsigned short* __restrict__ Wp2b)
{
    const int jt = blockIdx.x;
    const int h  = blockIdx.y;
    const int b  = blockIdx.z;

    __shared__ float sA[64][64];
    __shared__ float sW[64][64];

    const int t = threadIdx.x;
    {
        const float* A = attn + ((size_t)(b * 8 + h) << 12);
        for (int i = t * 4; i < 4096; i += 1024)
            *(float4*)&sA[0][i] = *(const float4*)(A + i);
    }
    {
        const int j  = t >> 2;
        const int c0 = (t & 3) * 16;
        #pragma unroll
        for (int i = 0; i < 4; ++i) {
            float4 w4 = *(const float4*)(Wp + (size_t)(jt * 64 + j) * DIMC + h * 64 + c0 + i * 4);
            sW[c0 + i * 4 + 0][j] = w4.x; sW[c0 + i * 4 + 1][j] = w4.y;
            sW[c0 + i * 4 + 2][j] = w4.z; sW[c0 + i * 4 + 3][j] = w4.w;
        }
    }
    __syncthreads();

    const int tx = t & 15, ty = t >> 4;
    float acc[4][4] = {};
    #pragma unroll 16
    for (int c = 0; c < 64; ++c) {
        float wf[4], af[4];
        #pragma unroll
        for (int i = 0; i < 4; ++i) { wf[i] = sW[c][ty * 4 + i]; af[i] = sA[c][tx * 4 + i]; }
        #pragma unroll
        for (int r = 0; r < 4; ++r)
            #pragma unroll
            for (int cc = 0; cc < 4; ++cc)
                acc[r][cc] = fmaf(wf[r], af[cc], acc[r][cc]);
    }

    unsigned short* O = Wp2b + ((size_t)b * DIMC + jt * 64 + ty * 4) * DIMC + h * 64 + tx * 4;
    #pragma unroll
    for (int r = 0; r < 4; ++r) {
        ushort4 o4;
        o4.x = f2bf(acc[r][0]); o4.y = f2bf(acc[r][1]);
        o4.z = f2bf(acc[r][2]); o4.w = f2bf(acc[r][3]);
        *(ushort4*)(O + (size_t)r * DIMC) = o4;
    }
}

// ---------------------------------------------------------------------------
// K6: final GEMM: out[b][j][n] = sum_c3 Wfb[b][j][c3] * xT[b][n][c3]
// (Wf = Wp2 * Wv folded; v never materialized). 128x128, fp32 direct stores.
// ---------------------------------------------------------------------------
__global__ __launch_bounds__(256) void final_mfma(
    const unsigned short* __restrict__ Wfb, const unsigned short* __restrict__ xT,
    float* __restrict__ out)
{
    const int b  = blockIdx.z;
    const int j0 = blockIdx.y * 128;
    const int n0 = blockIdx.x * 128;
    const unsigned short* A = Wfb + (size_t)b * DIMC * DIMC + (size_t)j0 * DIMC;
    const unsigned short* B = xT + (size_t)b * HW * DIMC + (size_t)n0 * DIMC;

    __shared__ __align__(16) char sm[65536];

    const int t = threadIdx.x, lane = t & 63, w = t >> 6;
    const int wm = w >> 1, wn = w & 1;
    const int rsub = lane >> 3;
    const int srccol = ((lane & 7) ^ rsub) << 3;

    f32x4 zero = {0.f, 0.f, 0.f, 0.f};
    f32x4 acc[4][4];
    #pragma unroll
    for (int m = 0; m < 4; ++m)
        #pragma unroll
        for (int n = 0; n < 4; ++n) acc[m][n] = zero;

    #define STAGE_FIN(buf, c0)                                                  \
        {                                                                       \
            char* dst = sm + (buf) * 32768;                                     \
            _Pragma("unroll")                                                   \
            for (int i = 0; i < 4; ++i) {                                       \
                int ii = w * 4 + i;                                             \
                gload_lds16(A + (size_t)(ii * 8 + rsub) * DIMC + (c0) + srccol, \
                            dst + ii * 1024);                                   \
                gload_lds16(B + (size_t)(ii * 8 + rsub) * DIMC + (c0) + srccol, \
                            dst + 16384 + ii * 1024);                           \
            }                                                                   \
        }

    STAGE_FIN(0, 0);
    int cur = 0;
    for (int c0 = 0; c0 < DIMC; c0 += 64) {
        __syncthreads();
        if (c0 + 64 < DIMC) STAGE_FIN(cur ^ 1, c0 + 64);
        const char* sA = sm + cur * 32768;
        const char* sB = sA + 16384;
        #pragma unroll
        for (int s = 0; s < 2; ++s) {
            bf16x8 af[4], bfr[4];
            #pragma unroll
            for (int m = 0; m < 4; ++m) {
                int r = wm * 64 + m * 16 + (lane & 15);
                int byte = r * 128 + s * 64 + ((lane >> 4) << 4);
                byte ^= (r & 7) << 4;
                af[m] = *(const bf16x8*)(sA + byte);
            }
            #pragma unroll
            for (int n = 0; n < 4; ++n) {
                int r = wn * 64 + n * 16 + (lane & 15);
                int byte = r * 128 + s * 64 + ((lane >> 4) << 4);
                byte ^= (r & 7) << 4;
                bfr[n] = *(const bf16x8*)(sB + byte);
            }
            #pragma unroll
            for (int m = 0; m < 4; ++m)
                #pragma unroll
                for (int n = 0; n < 4; ++n)
                    acc[m][n] = __builtin_amdgcn_mfma_f32_16x16x32_bf16(
                        af[m], bfr[n], acc[m][n], 0, 0, 0);
        }
        cur ^= 1;
    }
    #undef STAGE_FIN

    #pragma unroll
    for (int m = 0; m < 4; ++m)
        #pragma unroll
        for (int r4 = 0; r4 < 4; ++r4) {
            int j = j0 + wm * 64 + m * 16 + ((lane >> 4) << 2) + r4;
            size_t rowbase = ((size_t)b * DIMC + j) * HW + n0 + wn * 64 + (lane & 15);
            #pragma unroll
            for (int n = 0; n < 4; ++n)
                out[rowbase + n * 16] = acc[m][n][r4];
        }
}

// ---------------------------------------------------------------------------
// Workspace (bytes):
//   xT    @ 0           67,108,864   [b][n][c] bf16 unmasked
//   xmb   @ 67108864    67,108,864   [b][c][n] bf16 masked
//   Wb    @ 134217728    1,048,576   [Wq|Wk] bf16
//   WvT   @ 135266304      524,288   Wv^T bf16
//   G     @ 135790592    4,194,304   [b][512][512] bf16
//   TU    @ 139984896    8,388,608   [b][1024][512] bf16 (T=WqG | U=WkG)
//   sumsq @ 148373504       32,768   [2][8][512] fp32 (direct-written)
//   attn  @ 148406272    1,048,576   [bh][64][64] fp32
//   Wp2b  @ 149454848    4,194,304   bf16
//   Wfb   @ 153649152    4,194,304   bf16 (Wp2*Wv)
//   end ~157.8 MB
// ---------------------------------------------------------------------------
extern "C" void kernel_launch(void* const* d_in, const int* in_sizes, int n_in,
                              void* d_out, int out_size, void* d_ws, size_t ws_size,
                              hipStream_t stream)
{
    const float* x    = (const float*)d_in[0];
    const float* mask = (const float*)d_in[1];
    const float* Wq   = (const float*)d_in[2];
    const float* Wk   = (const float*)d_in[3];
    const float* Wv   = (const float*)d_in[4];
    const float* Wp   = (const float*)d_in[5];
    float* out = (float*)d_out;
    char* wsb = (char*)d_ws;

    unsigned short* xT   = (unsigned short*)(wsb + 0);
    unsigned short* xmb  = (unsigned short*)(wsb + 67108864);
    unsigned short* Wb   = (unsigned short*)(wsb + 134217728);
    unsigned short* WvT  = (unsigned short*)(wsb + 135266304);
    unsigned short* G    = (unsigned short*)(wsb + 135790592);
    unsigned short* TU   = (unsigned short*)(wsb + 139984896);
    float* sumsq         = (float*)(wsb + 148373504);
    float* attn          = (float*)(wsb + 148406272);
    unsigned short* Wp2b = (unsigned short*)(wsb + 149454848);
    unsigned short* Wfb  = (unsigned short*)(wsb + 153649152);

    convert_w  <<<512,             256, 0, stream>>>(Wq, Wk, Wb);
    wvt_conv   <<<dim3(8, 8),      256, 0, stream>>>(Wv, WvT);
    prep_x     <<<dim3(64, 8, 8),  256, 0, stream>>>(x, mask, xT, xmb);
    gram_mfma  <<<dim3(4, 8, 8),   256, 0, stream>>>(xmb, G);
    // TU[b] = [Wq|Wk] (1024x512) * G[b]  (B rows = G rows, valid: G symmetric)
    gemm_nn_128<<<dim3(4, 8, 8),   256, 0, stream>>>(Wb, (size_t)0, G, (size_t)(DIMC*DIMC), TU, (size_t)(1024*DIMC));
    sumsq_dot  <<<2048,            256, 0, stream>>>(TU, Wb, sumsq);
    s_softmax  <<<64,              256, 0, stream>>>(TU, Wb, sumsq, attn);
    build_wp2  <<<dim3(8, 8, 8),   256, 0, stream>>>(Wp, attn, Wp2b);
    // Wfb[b] = Wp2b[b] (512x512) * WvT rows  => Wp2 * Wv
    gemm_nn_128<<<dim3(4, 4, 8),   256, 0, stream>>>(Wp2b, (size_t)(DIMC*DIMC), WvT, (size_t)0, Wfb, (size_t)(DIMC*DIMC));
    final_mfma <<<dim3(32, 4, 8),  256, 0, stream>>>(Wfb, xT, out);
}